// Round 3
// baseline (237.636 us; speedup 1.0000x reference)
//
#include <hip/hip_runtime.h>
#include <math.h>

#define N_T 32768
#define L 65536
#define BATCH 64
#define NPACK 32
#define NRPACK 8
#define NEV 8
#define NROOM 16
#define DGATE 128
#define NC 8
#define NCP 9
#define NRW 8
#define TWO_PI 6.2831853071795864769f
#define INV_L (1.0f / 65536.0f)

__device__ __forceinline__ float2 cmul(float2 a, float2 b) {
    return make_float2(a.x * b.x - a.y * b.y, a.x * b.y + a.y * b.x);
}

// ---- gating: room softmax weights + mix ----
__global__ void k_prep(const float* __restrict__ g, const float* __restrict__ w_room,
                       const float* __restrict__ b_room, const float* __restrict__ w_mix,
                       const float* __restrict__ b_mix,
                       float* __restrict__ wroom, float* __restrict__ mixv) {
    int b = threadIdx.x;
    if (b >= BATCH) return;
    float logits[NROOM];
    for (int r = 0; r < NROOM; r++) logits[r] = b_room[r];
    float acc_mix = b_mix[0];
    for (int d = 0; d < DGATE; d++) {
        float gv = g[b * DGATE + d];
        for (int r = 0; r < NROOM; r++) logits[r] += gv * w_room[d * NROOM + r];
        acc_mix += gv * w_mix[d];
    }
    float m = logits[0];
    for (int r = 1; r < NROOM; r++) m = fmaxf(m, logits[r]);
    float s = 0.f;
    for (int r = 0; r < NROOM; r++) { logits[r] = expf(logits[r] - m); s += logits[r]; }
    float inv = 1.f / s;
    for (int r = 0; r < NROOM; r++) wroom[b * NROOM + r] = logits[r] * inv;
    mixv[b] = 1.f / (1.f + expf(-acc_mix));
}

// ---- build dry for batch pair (2p, 2p+1); pack as complex re/im ----
__global__ void k_dry(const float* __restrict__ events, const int* __restrict__ indices,
                      float* __restrict__ dryf, float2* __restrict__ C) {
    int gid = blockIdx.x * blockDim.x + threadIdx.x;  // NPACK * L/4
    int p = gid >> 14;
    int q = gid & 16383;
    int t0 = q << 2;
    float4* Cv = (float4*)(C + (size_t)p * L + t0);
    if (t0 < N_T) {
        float4 v0 = make_float4(0.f, 0.f, 0.f, 0.f);
        float4 v1 = make_float4(0.f, 0.f, 0.f, 0.f);
        const float* e0 = events + (size_t)(2 * p) * NEV * N_T;
        const float* e1 = e0 + (size_t)NEV * N_T;
        const int* i0 = indices + (2 * p) * NEV;
        const int* i1 = i0 + NEV;
#pragma unroll
        for (int e = 0; e < NEV; e++) {
            int n0 = t0 - (i0[e] << 8);
            if (n0 >= 0) {
                float4 ev = *(const float4*)(e0 + e * N_T + n0);
                v0.x += ev.x; v0.y += ev.y; v0.z += ev.z; v0.w += ev.w;
            }
            int n1 = t0 - (i1[e] << 8);
            if (n1 >= 0) {
                float4 ev = *(const float4*)(e1 + e * N_T + n1);
                v1.x += ev.x; v1.y += ev.y; v1.z += ev.z; v1.w += ev.w;
            }
        }
        *(float4*)(dryf + (size_t)(2 * p) * N_T + t0) = v0;
        *(float4*)(dryf + (size_t)(2 * p + 1) * N_T + t0) = v1;
        Cv[0] = make_float4(v0.x, v1.x, v0.y, v1.y);
        Cv[1] = make_float4(v0.z, v1.z, v0.w, v1.w);
    } else {
        Cv[0] = make_float4(0.f, 0.f, 0.f, 0.f);
        Cv[1] = make_float4(0.f, 0.f, 0.f, 0.f);
    }
}

// ---- pack rooms 2q, 2q+1 into complex ----
__global__ void k_spread_rooms(const float* __restrict__ rooms, float2* __restrict__ Cr) {
    int gid = blockIdx.x * blockDim.x + threadIdx.x;  // NRPACK * L/4
    int r = gid >> 14;
    int q = gid & 16383;
    int t0 = q << 2;
    float4* Cv = (float4*)(Cr + (size_t)r * L + t0);
    if (t0 < N_T) {
        float4 v0 = *(const float4*)(rooms + (size_t)(2 * r) * N_T + t0);
        float4 v1 = *(const float4*)(rooms + (size_t)(2 * r + 1) * N_T + t0);
        Cv[0] = make_float4(v0.x, v1.x, v0.y, v1.y);
        Cv[1] = make_float4(v0.z, v1.z, v0.w, v1.w);
    } else {
        Cv[0] = make_float4(0.f, 0.f, 0.f, 0.f);
        Cv[1] = make_float4(0.f, 0.f, 0.f, 0.f);
    }
}

// ---- forward four-step, column pass: FFT over n2 (stride 256) + twiddle ----
__global__ void k_fft_col_fwd(float2* __restrict__ C) {
    __shared__ float2 bufA[256 * NCP];
    __shared__ float2 bufB[256 * NCP];
    __shared__ float2 tw[128];
    int t = threadIdx.x;
    int a = blockIdx.x >> 5;
    int c0 = (blockIdx.x & 31) * NC;
    float2* base = C + (size_t)a * L;

    if (t < 128) {
        float sv, cv;
        __sincosf(-TWO_PI * (float)t / 256.0f, &sv, &cv);
        tw[t] = make_float2(cv, sv);
    }
    for (int k = t; k < 1024; k += 256) {       // col pairs: 2 cols per thread, float4
        int cp = k & 3;
        int e = k >> 2;
        float4 v = *(const float4*)(base + (c0 + 2 * cp) + (e << 8));
        bufA[e * NCP + 2 * cp]     = make_float2(v.x, v.y);
        bufA[e * NCP + 2 * cp + 1] = make_float2(v.z, v.w);
    }
    __syncthreads();
    float2* src = bufA;
    float2* dst = bufB;
    for (int s = 1; s <= 128; s <<= 1) {
        for (int w = t; w < 1024; w += 256) {
            int c = w & (NC - 1);
            int j = w >> 3;
            int ps = j & ~(s - 1);
            float2 x0 = src[j * NCP + c];
            float2 x1 = src[(j + 128) * NCP + c];
            float2 wp = tw[ps];
            dst[(j + ps) * NCP + c] = make_float2(x0.x + x1.x, x0.y + x1.y);
            dst[(j + ps + s) * NCP + c] = cmul(make_float2(x0.x - x1.x, x0.y - x1.y), wp);
        }
        __syncthreads();
        float2* tmp = src; src = dst; dst = tmp;
    }
    for (int k = t; k < 1024; k += 256) {
        int cp = k & 3;
        int k2 = k >> 2;
        int n1a = c0 + 2 * cp;
        float2 va = src[k2 * NCP + 2 * cp];
        float2 vb = src[k2 * NCP + 2 * cp + 1];
        int pha = (n1a * k2) & (L - 1);
        int phb = ((n1a + 1) * k2) & (L - 1);
        float sa, ca, sb, cb;
        __sincosf(-TWO_PI * (float)pha * INV_L, &sa, &ca);
        __sincosf(-TWO_PI * (float)phb * INV_L, &sb, &cb);
        float2 ra = cmul(va, make_float2(ca, sa));
        float2 rb = cmul(vb, make_float2(cb, sb));
        *(float4*)(base + n1a + (k2 << 8)) = make_float4(ra.x, ra.y, rb.x, rb.y);
    }
}

// ---- four-step row pass: FFT over contiguous n1 ----
template <bool INV>
__global__ void k_fft_row(float2* __restrict__ C) {
    __shared__ float2 bufA[NRW * 256];
    __shared__ float2 bufB[NRW * 256];
    __shared__ float2 tw[128];
    int t = threadIdx.x;
    int a = blockIdx.x >> 5;
    int r0 = (blockIdx.x & 31) * NRW;
    float2* chunk = C + (size_t)a * L + (size_t)r0 * 256;

    if (t < 128) {
        float sv, cv;
        __sincosf(-TWO_PI * (float)t / 256.0f, &sv, &cv);
        tw[t] = make_float2(cv, INV ? -sv : sv);
    }
    for (int k = t; k < 1024; k += 256) {
        float4 v = *(const float4*)(chunk + 2 * k);
        bufA[2 * k]     = make_float2(v.x, v.y);
        bufA[2 * k + 1] = make_float2(v.z, v.w);
    }
    __syncthreads();
    float2* src = bufA;
    float2* dst = bufB;
    for (int s = 1; s <= 128; s <<= 1) {
        for (int w = t; w < 1024; w += 256) {
            int rr = w >> 7;
            int j = w & 127;
            int ps = j & ~(s - 1);
            int rb = rr << 8;
            float2 x0 = src[rb + j];
            float2 x1 = src[rb + j + 128];
            float2 wp = tw[ps];
            dst[rb + j + ps] = make_float2(x0.x + x1.x, x0.y + x1.y);
            dst[rb + j + ps + s] = cmul(make_float2(x0.x - x1.x, x0.y - x1.y), wp);
        }
        __syncthreads();
        float2* tmp = src; src = dst; dst = tmp;
    }
    for (int k = t; k < 1024; k += 256) {
        int m = 2 * k;
        float2 va = src[m];
        float2 vb = src[m + 1];
        if (!INV) {
            *(float4*)(chunk + m) = make_float4(va.x, va.y, vb.x, vb.y);
        } else {
            int rr = m >> 8;
            int n1 = m & 255;
            int k2 = r0 + rr;
            int pha = (n1 * k2) & (L - 1);
            int phb = ((n1 + 1) * k2) & (L - 1);
            float sa, ca, sb, cb;
            __sincosf(TWO_PI * (float)pha * INV_L, &sa, &ca);
            __sincosf(TWO_PI * (float)phb * INV_L, &sb, &cb);
            float2 ra = cmul(va, make_float2(ca, sa));
            float2 rb = cmul(vb, make_float2(cb, sb));
            *(float4*)(chunk + m) = make_float4(ra.x, ra.y, rb.x, rb.y);
        }
    }
}

// ---- pointwise with real-pair separation, in scrambled order ----
// addr j = k2*256 + k1 holds X[k2 + 256*k1]; partner of k is -k mod L:
//   k2==0: jn = (256-k1)&255 ; k2>0: jn = (256-k2)*256 + (255-k1)
__device__ __forceinline__ void pw_process(float2* __restrict__ C, const float* __restrict__ wr,
                                           int j, int jn, int pg) {
    const float2* Zr = C + (size_t)NPACK * L;
    float2 R[NROOM];
#pragma unroll
    for (int q = 0; q < NRPACK; q++) {
        float2 A = Zr[(size_t)q * L + j];
        float2 B = Zr[(size_t)q * L + jn];
        R[2 * q]     = make_float2(0.5f * (A.x + B.x), 0.5f * (A.y - B.y));
        R[2 * q + 1] = make_float2(0.5f * (A.y + B.y), 0.5f * (B.x - A.x));
    }
    for (int p = pg * 16; p < pg * 16 + 16; p++) {
        float2 Zj = C[(size_t)p * L + j];
        float2 Zn = C[(size_t)p * L + jn];
        float2 D0 = make_float2(0.5f * (Zj.x + Zn.x), 0.5f * (Zj.y - Zn.y));
        float2 D1 = make_float2(0.5f * (Zj.y + Zn.y), 0.5f * (Zn.x - Zj.x));
        const float* w0 = wr + (2 * p) * NROOM;
        const float* w1 = w0 + NROOM;
        float2 K0 = make_float2(0.f, 0.f);
        float2 K1 = make_float2(0.f, 0.f);
#pragma unroll
        for (int r = 0; r < NROOM; r++) {
            float2 rv = R[r];
            K0.x += w0[r] * rv.x; K0.y += w0[r] * rv.y;
            K1.x += w1[r] * rv.x; K1.y += w1[r] * rv.y;
        }
        float2 W0 = cmul(D0, K0);
        float2 W1 = cmul(D1, K1);
        C[(size_t)p * L + j]  = make_float2(W0.x - W1.y, W0.y + W1.x);
        C[(size_t)p * L + jn] = make_float2(W0.x + W1.y, W1.x - W0.y);
    }
}

__global__ void k_pw(float2* __restrict__ C, const float* __restrict__ wroom) {
    __shared__ float wr[BATCH * NROOM];
    int t = threadIdx.x;
    for (int i = t; i < BATCH * NROOM; i += 256) wr[i] = wroom[i];
    __syncthreads();
    int pg = blockIdx.x & 1;                  // batch-pair half: p in [16*pg, 16*pg+16)
    int h = (blockIdx.x >> 1) * 256 + t;      // [0, 32768) pair index
    int j, jn;
    bool dual = false;
    if (h < 32512) {               // rows 1..127 paired with 255..129
        int row = 1 + (h >> 8);
        int k1 = h & 255;
        j = (row << 8) + k1;
        jn = ((256 - row) << 8) + (255 - k1);
    } else if (h < 32640) {        // row 128 internal pairs
        int k1 = h - 32512;        // [0,128)
        j = (128 << 8) + k1;
        jn = (128 << 8) + 255 - k1;
    } else {                       // row 0: (k1, 256-k1); k1=0 self, also do 128 self
        int k1 = h - 32640;        // [0,128)
        j = k1;
        jn = (256 - k1) & 255;
        dual = (k1 == 0);
    }
    pw_process(C, wr, j, jn, pg);
    if (dual) pw_process(C, wr, 128, 128, pg);
}

// ---- inverse column pass fused with mix + per-block partial max ----
__global__ void k_fft_col_inv(float2* __restrict__ C, const float* __restrict__ dryf,
                              const float* __restrict__ mixv, float* __restrict__ out,
                              float* __restrict__ partial) {
    __shared__ float2 bufA[256 * NCP];
    __shared__ float2 bufB[256 * NCP];
    __shared__ float2 tw[128];
    int t = threadIdx.x;
    int a = blockIdx.x >> 5;
    int cb = blockIdx.x & 31;
    int c0 = cb * NC;
    float2* base = C + (size_t)a * L;

    if (t < 128) {
        float sv, cv;
        __sincosf(-TWO_PI * (float)t / 256.0f, &sv, &cv);
        tw[t] = make_float2(cv, -sv);
    }
    for (int k = t; k < 1024; k += 256) {
        int cp = k & 3;
        int e = k >> 2;
        float4 v = *(const float4*)(base + (c0 + 2 * cp) + (e << 8));
        bufA[e * NCP + 2 * cp]     = make_float2(v.x, v.y);
        bufA[e * NCP + 2 * cp + 1] = make_float2(v.z, v.w);
    }
    __syncthreads();
    float2* src = bufA;
    float2* dst = bufB;
    for (int s = 1; s <= 128; s <<= 1) {
        for (int w = t; w < 1024; w += 256) {
            int c = w & (NC - 1);
            int j = w >> 3;
            int ps = j & ~(s - 1);
            float2 x0 = src[j * NCP + c];
            float2 x1 = src[(j + 128) * NCP + c];
            float2 wp = tw[ps];
            dst[(j + ps) * NCP + c] = make_float2(x0.x + x1.x, x0.y + x1.y);
            dst[(j + ps + s) * NCP + c] = cmul(make_float2(x0.x - x1.x, x0.y - x1.y), wp);
        }
        __syncthreads();
        float2* tmp = src; src = dst; dst = tmp;
    }
    int b0 = 2 * a, b1 = 2 * a + 1;
    float mix0 = mixv[b0], mix1 = mixv[b1];
    float om0 = 1.f - mix0, om1 = 1.f - mix1;
    const float* dry0 = dryf + (size_t)b0 * N_T;
    const float* dry1 = dryf + (size_t)b1 * N_T;
    float* out0 = out + (size_t)b0 * N_T;
    float* out1 = out + (size_t)b1 * N_T;
    float m0 = -3.4e38f, m1 = -3.4e38f;
    for (int k = t; k < 1024; k += 256) {
        int cp = k & 3;
        int n2 = k >> 2;
        if (n2 < 128) {
            int pos = (c0 + 2 * cp) + (n2 << 8);
            float2 va = src[n2 * NCP + 2 * cp];
            float2 vb = src[n2 * NCP + 2 * cp + 1];
            float2 d0 = *(const float2*)(dry0 + pos);
            float2 d1 = *(const float2*)(dry1 + pos);
            float o0a = mix0 * (va.x * INV_L) + om0 * d0.x;
            float o0b = mix0 * (vb.x * INV_L) + om0 * d0.y;
            float o1a = mix1 * (va.y * INV_L) + om1 * d1.x;
            float o1b = mix1 * (vb.y * INV_L) + om1 * d1.y;
            *(float2*)(out0 + pos) = make_float2(o0a, o0b);
            *(float2*)(out1 + pos) = make_float2(o1a, o1b);
            m0 = fmaxf(m0, fmaxf(o0a, o0b));
            m1 = fmaxf(m1, fmaxf(o1a, o1b));
        }
    }
#pragma unroll
    for (int off = 32; off > 0; off >>= 1) {
        m0 = fmaxf(m0, __shfl_down(m0, off));
        m1 = fmaxf(m1, __shfl_down(m1, off));
    }
    __shared__ float sm0[4], sm1[4];
    if ((t & 63) == 0) { sm0[t >> 6] = m0; sm1[t >> 6] = m1; }
    __syncthreads();
    if (t == 0) {
        partial[b0 * 32 + cb] = fmaxf(fmaxf(sm0[0], sm0[1]), fmaxf(sm0[2], sm0[3]));
        partial[b1 * 32 + cb] = fmaxf(fmaxf(sm1[0], sm1[1]), fmaxf(sm1[2], sm1[3]));
    }
}

__global__ void k_norm(float* __restrict__ out, const float* __restrict__ partial) {
    int blk = blockIdx.x;
    int b = blk >> 5;
    int ch = blk & 31;
    __shared__ float smx;
    if (threadIdx.x < 32) {
        float p = partial[b * 32 + threadIdx.x];
#pragma unroll
        for (int off = 16; off > 0; off >>= 1) p = fmaxf(p, __shfl_down(p, off, 32));
        if (threadIdx.x == 0) smx = p;
    }
    __syncthreads();
    float inv = 1.f / (smx + 1e-8f);
    size_t base = (size_t)b * N_T + ch * 1024 + threadIdx.x * 4;
    float4 o = *(const float4*)(out + base);
    o.x *= inv; o.y *= inv; o.z *= inv; o.w *= inv;
    *(float4*)(out + base) = o;
}

extern "C" void kernel_launch(void* const* d_in, const int* in_sizes, int n_in,
                              void* d_out, int out_size, void* d_ws, size_t ws_size,
                              hipStream_t stream) {
    const float* events = (const float*)d_in[0];
    const int* indices = (const int*)d_in[1];
    const float* g      = (const float*)d_in[2];
    const float* rooms  = (const float*)d_in[3];
    const float* w_room = (const float*)d_in[4];
    const float* b_room = (const float*)d_in[5];
    const float* w_mix  = (const float*)d_in[6];
    const float* b_mix  = (const float*)d_in[7];
    float* out = (float*)d_out;

    char* ws = (char*)d_ws;
    float2* C = (float2*)ws;  // [40][65536]: 0..31 packed dry pairs, 32..39 packed rooms
    size_t off = (size_t)(NPACK + NRPACK) * L * sizeof(float2);
    float* dryf = (float*)(ws + off);
    off += (size_t)BATCH * N_T * sizeof(float);
    float* wroom = (float*)(ws + off);
    off += BATCH * NROOM * sizeof(float);
    float* mixv = (float*)(ws + off);
    off += BATCH * sizeof(float);
    float* partial = (float*)(ws + off);

    k_prep<<<1, 64, 0, stream>>>(g, w_room, b_room, w_mix, b_mix, wroom, mixv);
    k_dry<<<NPACK * (L / 4) / 256, 256, 0, stream>>>(events, indices, dryf, C);
    k_spread_rooms<<<NRPACK * (L / 4) / 256, 256, 0, stream>>>(rooms, C + (size_t)NPACK * L);
    k_fft_col_fwd<<<(NPACK + NRPACK) * 32, 256, 0, stream>>>(C);
    k_fft_row<false><<<(NPACK + NRPACK) * 32, 256, 0, stream>>>(C);
    k_pw<<<256, 256, 0, stream>>>(C, wroom);
    k_fft_row<true><<<NPACK * 32, 256, 0, stream>>>(C);
    k_fft_col_inv<<<NPACK * 32, 256, 0, stream>>>(C, dryf, mixv, out, partial);
    k_norm<<<BATCH * 32, 256, 0, stream>>>(out, partial);
}

// Round 4
// 127.733 us; speedup vs baseline: 1.8604x; 1.8604x over previous
//
#include <hip/hip_runtime.h>
#include <math.h>

#define N_T 32768
#define L 65536
#define BATCH 64
#define NPAIR 32
#define NEV 8
#define NROOM 16
#define DGATE 128
#define NC 8
#define NCP 9
#define TWO_PI 6.2831853071795864769f
#define INV_L (1.0f / 65536.0f)

__device__ __forceinline__ float2 cmul(float2 a, float2 b) {
    return make_float2(a.x * b.x - a.y * b.y, a.x * b.y + a.y * b.x);
}

// ---- gating: room softmax weights + mix ----
__global__ void k_prep(const float* __restrict__ g, const float* __restrict__ w_room,
                       const float* __restrict__ b_room, const float* __restrict__ w_mix,
                       const float* __restrict__ b_mix,
                       float* __restrict__ wroom, float* __restrict__ mixv) {
    int b = threadIdx.x;
    if (b >= BATCH) return;
    float logits[NROOM];
    for (int r = 0; r < NROOM; r++) logits[r] = b_room[r];
    float acc_mix = b_mix[0];
    for (int d = 0; d < DGATE; d++) {
        float gv = g[b * DGATE + d];
        for (int r = 0; r < NROOM; r++) logits[r] += gv * w_room[d * NROOM + r];
        acc_mix += gv * w_mix[d];
    }
    float m = logits[0];
    for (int r = 1; r < NROOM; r++) m = fmaxf(m, logits[r]);
    float s = 0.f;
    for (int r = 0; r < NROOM; r++) { logits[r] = expf(logits[r] - m); s += logits[r]; }
    float inv = 1.f / s;
    for (int r = 0; r < NROOM; r++) wroom[b * NROOM + r] = logits[r] * inv;
    mixv[b] = 1.f / (1.f + expf(-acc_mix));
}

// ---- build dry_b and time-domain mixed kernel K_b; pack Z_b = dry_b + i*K_b ----
__global__ void k_dry(const float* __restrict__ events, const int* __restrict__ indices,
                      const float* __restrict__ rooms, const float* __restrict__ wroom,
                      float* __restrict__ dryf, float2* __restrict__ C) {
    int gid = blockIdx.x * blockDim.x + threadIdx.x;  // BATCH * L/4
    int b = gid >> 14;
    int q = gid & 16383;
    int t0 = q << 2;
    float2* Cb = C + (size_t)b * L + t0;
    if (t0 < N_T) {
        const float* eb = events + (size_t)b * NEV * N_T;
        const int* ib = indices + b * NEV;
        float4 v = make_float4(0.f, 0.f, 0.f, 0.f);
#pragma unroll
        for (int e = 0; e < NEV; e++) {
            int n = t0 - (ib[e] << 8);
            if (n >= 0) {  // t0, start both multiples of 4
                float4 ev = *(const float4*)(eb + e * N_T + n);
                v.x += ev.x; v.y += ev.y; v.z += ev.z; v.w += ev.w;
            }
        }
        const float* wb = wroom + b * NROOM;
        float4 kk = make_float4(0.f, 0.f, 0.f, 0.f);
#pragma unroll
        for (int r = 0; r < NROOM; r++) {
            float w = wb[r];
            float4 rv = *(const float4*)(rooms + (size_t)r * N_T + t0);
            kk.x += w * rv.x; kk.y += w * rv.y; kk.z += w * rv.z; kk.w += w * rv.w;
        }
        *(float4*)(dryf + (size_t)b * N_T + t0) = v;
        ((float4*)Cb)[0] = make_float4(v.x, kk.x, v.y, kk.y);
        ((float4*)Cb)[1] = make_float4(v.z, kk.z, v.w, kk.w);
    } else {
        ((float4*)Cb)[0] = make_float4(0.f, 0.f, 0.f, 0.f);
        ((float4*)Cb)[1] = make_float4(0.f, 0.f, 0.f, 0.f);
    }
}

// ---- forward four-step, column pass: FFT over n2 (stride 256) + big twiddle ----
__global__ void k_fft_col_fwd(float2* __restrict__ C) {
    __shared__ float2 bufA[256 * NCP];
    __shared__ float2 bufB[256 * NCP];
    __shared__ float2 tw[128];
    int t = threadIdx.x;
    int a = blockIdx.x >> 5;
    int c0 = (blockIdx.x & 31) * NC;
    float2* base = C + (size_t)a * L;

    if (t < 128) {
        float sv, cv;
        __sincosf(-TWO_PI * (float)t / 256.0f, &sv, &cv);
        tw[t] = make_float2(cv, sv);
    }
    for (int k = t; k < 1024; k += 256) {
        int cp = k & 3;
        int e = k >> 2;
        float4 v = *(const float4*)(base + (c0 + 2 * cp) + (e << 8));
        bufA[e * NCP + 2 * cp]     = make_float2(v.x, v.y);
        bufA[e * NCP + 2 * cp + 1] = make_float2(v.z, v.w);
    }
    __syncthreads();
    float2* src = bufA;
    float2* dst = bufB;
    for (int s = 1; s <= 128; s <<= 1) {
        for (int w = t; w < 1024; w += 256) {
            int c = w & (NC - 1);
            int j = w >> 3;
            int ps = j & ~(s - 1);
            float2 x0 = src[j * NCP + c];
            float2 x1 = src[(j + 128) * NCP + c];
            float2 wp = tw[ps];
            dst[(j + ps) * NCP + c] = make_float2(x0.x + x1.x, x0.y + x1.y);
            dst[(j + ps + s) * NCP + c] = cmul(make_float2(x0.x - x1.x, x0.y - x1.y), wp);
        }
        __syncthreads();
        float2* tmp = src; src = dst; dst = tmp;
    }
    for (int k = t; k < 1024; k += 256) {
        int cp = k & 3;
        int k2 = k >> 2;
        int n1a = c0 + 2 * cp;
        float2 va = src[k2 * NCP + 2 * cp];
        float2 vb = src[k2 * NCP + 2 * cp + 1];
        int pha = (n1a * k2) & (L - 1);
        int phb = ((n1a + 1) * k2) & (L - 1);
        float sa, ca, sb, cb;
        __sincosf(-TWO_PI * (float)pha * INV_L, &sa, &ca);
        __sincosf(-TWO_PI * (float)phb * INV_L, &sb, &cb);
        float2 ra = cmul(va, make_float2(ca, sa));
        float2 rb = cmul(vb, make_float2(cb, sb));
        *(float4*)(base + n1a + (k2 << 8)) = make_float4(ra.x, ra.y, rb.x, rb.y);
    }
}

// ---- mirror row group: slot s (0..7) -> k2 row index ----
__device__ __forceinline__ int row_of(int g, int s) {
    int i = s & 3;
    if (s < 4) return 4 * g + i;
    return (g == 0) ? (i == 0 ? 128 : 256 - i) : 256 - 4 * g - i;
}

// ---- pointwise unit: pair (slotJ,kJ) <-> (slotN,kN); arrays 0/1 at LDS slots s / 8+s ----
__device__ __forceinline__ void pw_unit(const float2* __restrict__ A, float2* __restrict__ Y,
                                        int sJ, int kJ, int sN, int kN) {
    float2 Z0j = A[sJ * 256 + kJ],      Z0n = A[sN * 256 + kN];
    float2 Z1j = A[(8 + sJ) * 256 + kJ], Z1n = A[(8 + sN) * 256 + kN];
    float2 D0 = make_float2(0.5f * (Z0j.x + Z0n.x), 0.5f * (Z0j.y - Z0n.y));
    float2 K0 = make_float2(0.5f * (Z0j.y + Z0n.y), 0.5f * (Z0n.x - Z0j.x));
    float2 D1 = make_float2(0.5f * (Z1j.x + Z1n.x), 0.5f * (Z1j.y - Z1n.y));
    float2 K1 = make_float2(0.5f * (Z1j.y + Z1n.y), 0.5f * (Z1n.x - Z1j.x));
    float2 W0 = cmul(D0, K0);
    float2 W1 = cmul(D1, K1);
    Y[sJ * 256 + kJ] = make_float2(W0.x - W1.y, W0.y + W1.x);
    Y[sN * 256 + kN] = make_float2(W0.x + W1.y, W1.x - W0.y);
}

// ---- fused: fwd row FFT (2 arrays x 8 mirror rows) -> pointwise -> inv row FFT ----
// writes packed Y_p rows in-place into array 2p (rows owned exclusively by this block)
__global__ void k_rowpw(float2* __restrict__ C) {
    __shared__ float2 A[16 * 256];
    __shared__ float2 Bsh[16 * 256];
    __shared__ float2 tw[128];
    int t = threadIdx.x;
    int p = blockIdx.x >> 5;
    int g = blockIdx.x & 31;
    if (t < 128) {
        float sv, cv;
        __sincosf(-TWO_PI * (float)t / 256.0f, &sv, &cv);
        tw[t] = make_float2(cv, sv);
    }
    float2* b0 = C + (size_t)(2 * p) * L;
    float2* b1 = b0 + L;
    for (int u = t; u < 2048; u += 256) {
        int slot = u >> 7;
        int f = (u & 127) << 1;
        int k2v = row_of(g, slot & 7);
        const float2* arr = (slot < 8) ? b0 : b1;
        float4 v = *(const float4*)(arr + (k2v << 8) + f);
        A[slot * 256 + f]     = make_float2(v.x, v.y);
        A[slot * 256 + f + 1] = make_float2(v.z, v.w);
    }
    __syncthreads();
    float2* src = A;
    float2* dst = Bsh;
    for (int s = 1; s <= 128; s <<= 1) {      // 16 forward row FFTs
        for (int w = t; w < 2048; w += 256) {
            int rb = (w >> 7) << 8;
            int j = w & 127;
            int ps = j & ~(s - 1);
            float2 x0 = src[rb + j];
            float2 x1 = src[rb + j + 128];
            float2 wp = tw[ps];
            dst[rb + j + ps] = make_float2(x0.x + x1.x, x0.y + x1.y);
            dst[rb + j + ps + s] = cmul(make_float2(x0.x - x1.x, x0.y - x1.y), wp);
        }
        __syncthreads();
        float2* tmp = src; src = dst; dst = tmp;
    }
    // src == A holds spectra; write Y into Bsh rows 0..7
    if (g) {
        pw_unit(A, Bsh, 0, t, 4, 255 - t);
    } else {
        if (t < 128) pw_unit(A, Bsh, 0, t, 0, (256 - t) & 255);
        else         pw_unit(A, Bsh, 4, t - 128, 4, 383 - t);
        if (t == 0)  pw_unit(A, Bsh, 0, 128, 0, 128);
    }
    pw_unit(A, Bsh, 1, t, 5, 255 - t);
    pw_unit(A, Bsh, 2, t, 6, 255 - t);
    pw_unit(A, Bsh, 3, t, 7, 255 - t);
    __syncthreads();
    src = Bsh;
    dst = A;
    for (int s = 1; s <= 128; s <<= 1) {      // 8 inverse row FFTs
        for (int w = t; w < 1024; w += 256) {
            int rb = (w >> 7) << 8;
            int j = w & 127;
            int ps = j & ~(s - 1);
            float2 x0 = src[rb + j];
            float2 x1 = src[rb + j + 128];
            float2 wp = make_float2(tw[ps].x, -tw[ps].y);
            dst[rb + j + ps] = make_float2(x0.x + x1.x, x0.y + x1.y);
            dst[rb + j + ps + s] = cmul(make_float2(x0.x - x1.x, x0.y - x1.y), wp);
        }
        __syncthreads();
        float2* tmp = src; src = dst; dst = tmp;
    }
    // src == Bsh: inverse big twiddle + store into array 2p, same rows
    for (int u = t; u < 1024; u += 256) {
        int slot = u >> 7;
        int f = (u & 127) << 1;
        int k2v = row_of(g, slot);
        float2 va = Bsh[slot * 256 + f];
        float2 vb = Bsh[slot * 256 + f + 1];
        int pha = (f * k2v) & (L - 1);
        int phb = ((f + 1) * k2v) & (L - 1);
        float sa, ca, sb, cb;
        __sincosf(TWO_PI * (float)pha * INV_L, &sa, &ca);
        __sincosf(TWO_PI * (float)phb * INV_L, &sb, &cb);
        float2 ra = cmul(va, make_float2(ca, sa));
        float2 rb2 = cmul(vb, make_float2(cb, sb));
        *(float4*)(b0 + (k2v << 8) + f) = make_float4(ra.x, ra.y, rb2.x, rb2.y);
    }
}

// ---- inverse column pass fused with mix + per-block partial max ----
__global__ void k_fft_col_inv(float2* __restrict__ C, const float* __restrict__ dryf,
                              const float* __restrict__ mixv, float* __restrict__ out,
                              float* __restrict__ partial) {
    __shared__ float2 bufA[256 * NCP];
    __shared__ float2 bufB[256 * NCP];
    __shared__ float2 tw[128];
    int t = threadIdx.x;
    int a = blockIdx.x >> 5;        // pair index
    int cb = blockIdx.x & 31;
    int c0 = cb * NC;
    float2* base = C + (size_t)(2 * a) * L;   // packed result lives in array 2a

    if (t < 128) {
        float sv, cv;
        __sincosf(-TWO_PI * (float)t / 256.0f, &sv, &cv);
        tw[t] = make_float2(cv, -sv);
    }
    for (int k = t; k < 1024; k += 256) {
        int cp = k & 3;
        int e = k >> 2;
        float4 v = *(const float4*)(base + (c0 + 2 * cp) + (e << 8));
        bufA[e * NCP + 2 * cp]     = make_float2(v.x, v.y);
        bufA[e * NCP + 2 * cp + 1] = make_float2(v.z, v.w);
    }
    __syncthreads();
    float2* src = bufA;
    float2* dst = bufB;
    for (int s = 1; s <= 128; s <<= 1) {
        for (int w = t; w < 1024; w += 256) {
            int c = w & (NC - 1);
            int j = w >> 3;
            int ps = j & ~(s - 1);
            float2 x0 = src[j * NCP + c];
            float2 x1 = src[(j + 128) * NCP + c];
            float2 wp = tw[ps];
            dst[(j + ps) * NCP + c] = make_float2(x0.x + x1.x, x0.y + x1.y);
            dst[(j + ps + s) * NCP + c] = cmul(make_float2(x0.x - x1.x, x0.y - x1.y), wp);
        }
        __syncthreads();
        float2* tmp = src; src = dst; dst = tmp;
    }
    int b0 = 2 * a, b1 = 2 * a + 1;
    float mix0 = mixv[b0], mix1 = mixv[b1];
    float om0 = 1.f - mix0, om1 = 1.f - mix1;
    const float* dry0 = dryf + (size_t)b0 * N_T;
    const float* dry1 = dryf + (size_t)b1 * N_T;
    float* out0 = out + (size_t)b0 * N_T;
    float* out1 = out + (size_t)b1 * N_T;
    float m0 = -3.4e38f, m1 = -3.4e38f;
    for (int k = t; k < 1024; k += 256) {
        int cp = k & 3;
        int n2 = k >> 2;
        if (n2 < 128) {
            int pos = (c0 + 2 * cp) + (n2 << 8);
            float2 va = src[n2 * NCP + 2 * cp];
            float2 vb = src[n2 * NCP + 2 * cp + 1];
            float2 d0 = *(const float2*)(dry0 + pos);
            float2 d1 = *(const float2*)(dry1 + pos);
            float o0a = mix0 * (va.x * INV_L) + om0 * d0.x;
            float o0b = mix0 * (vb.x * INV_L) + om0 * d0.y;
            float o1a = mix1 * (va.y * INV_L) + om1 * d1.x;
            float o1b = mix1 * (vb.y * INV_L) + om1 * d1.y;
            *(float2*)(out0 + pos) = make_float2(o0a, o0b);
            *(float2*)(out1 + pos) = make_float2(o1a, o1b);
            m0 = fmaxf(m0, fmaxf(o0a, o0b));
            m1 = fmaxf(m1, fmaxf(o1a, o1b));
        }
    }
#pragma unroll
    for (int off = 32; off > 0; off >>= 1) {
        m0 = fmaxf(m0, __shfl_down(m0, off));
        m1 = fmaxf(m1, __shfl_down(m1, off));
    }
    __shared__ float sm0[4], sm1[4];
    if ((t & 63) == 0) { sm0[t >> 6] = m0; sm1[t >> 6] = m1; }
    __syncthreads();
    if (t == 0) {
        partial[b0 * 32 + cb] = fmaxf(fmaxf(sm0[0], sm0[1]), fmaxf(sm0[2], sm0[3]));
        partial[b1 * 32 + cb] = fmaxf(fmaxf(sm1[0], sm1[1]), fmaxf(sm1[2], sm1[3]));
    }
}

__global__ void k_norm(float* __restrict__ out, const float* __restrict__ partial) {
    int blk = blockIdx.x;
    int b = blk >> 5;
    int ch = blk & 31;
    __shared__ float smx;
    if (threadIdx.x < 32) {
        float p = partial[b * 32 + threadIdx.x];
#pragma unroll
        for (int off = 16; off > 0; off >>= 1) p = fmaxf(p, __shfl_down(p, off, 32));
        if (threadIdx.x == 0) smx = p;
    }
    __syncthreads();
    float inv = 1.f / (smx + 1e-8f);
    size_t base = (size_t)b * N_T + ch * 1024 + threadIdx.x * 4;
    float4 o = *(const float4*)(out + base);
    o.x *= inv; o.y *= inv; o.z *= inv; o.w *= inv;
    *(float4*)(out + base) = o;
}

extern "C" void kernel_launch(void* const* d_in, const int* in_sizes, int n_in,
                              void* d_out, int out_size, void* d_ws, size_t ws_size,
                              hipStream_t stream) {
    const float* events = (const float*)d_in[0];
    const int* indices = (const int*)d_in[1];
    const float* g      = (const float*)d_in[2];
    const float* rooms  = (const float*)d_in[3];
    const float* w_room = (const float*)d_in[4];
    const float* b_room = (const float*)d_in[5];
    const float* w_mix  = (const float*)d_in[6];
    const float* b_mix  = (const float*)d_in[7];
    float* out = (float*)d_out;

    char* ws = (char*)d_ws;
    float2* C = (float2*)ws;  // [64][65536] complex: Z_b = dry_b + i*K_b
    size_t off = (size_t)BATCH * L * sizeof(float2);
    float* dryf = (float*)(ws + off);
    off += (size_t)BATCH * N_T * sizeof(float);
    float* wroom = (float*)(ws + off);
    off += BATCH * NROOM * sizeof(float);
    float* mixv = (float*)(ws + off);
    off += BATCH * sizeof(float);
    float* partial = (float*)(ws + off);

    k_prep<<<1, 64, 0, stream>>>(g, w_room, b_room, w_mix, b_mix, wroom, mixv);
    k_dry<<<BATCH * (L / 4) / 256, 256, 0, stream>>>(events, indices, rooms, wroom, dryf, C);
    k_fft_col_fwd<<<BATCH * 32, 256, 0, stream>>>(C);
    k_rowpw<<<NPAIR * 32, 256, 0, stream>>>(C);
    k_fft_col_inv<<<NPAIR * 32, 256, 0, stream>>>(C, dryf, mixv, out, partial);
    k_norm<<<BATCH * 32, 256, 0, stream>>>(out, partial);
}

// Round 5
// 104.216 us; speedup vs baseline: 2.2802x; 1.2257x over previous
//
#include <hip/hip_runtime.h>
#include <math.h>

#define N_T 32768
#define L 65536
#define BATCH 64
#define NPAIR 32
#define NEV 8
#define NROOM 16
#define DGATE 128
#define NC 8
#define NCP 9
#define ROWP 258
#define TWO_PI 6.2831853071795864769f
#define INV_L (1.0f / 65536.0f)

__device__ __forceinline__ float2 cmul(float2 a, float2 b) {
    return make_float2(a.x * b.x - a.y * b.y, a.x * b.y + a.y * b.x);
}
// base-4 digit reversal of an 8-bit index (involution)
__device__ __forceinline__ int dr4(int p) {
    return ((p & 3) << 6) | ((p & 12) << 2) | ((p & 48) >> 2) | ((p & 192) >> 6);
}

// in-place radix-4 DIF butterfly (fwd): y_j = DFT4_j(x) * W_m^{qj}, stored at a0+j*st
__device__ __forceinline__ void bfly4_fwd(float2* A, int a0, int st, const float2* tw, int f, int q) {
    float2 a = A[a0], b = A[a0 + st], c = A[a0 + 2 * st], d = A[a0 + 3 * st];
    float2 t0 = make_float2(a.x + c.x, a.y + c.y);
    float2 t1 = make_float2(a.x - c.x, a.y - c.y);
    float2 t2 = make_float2(b.x + d.x, b.y + d.y);
    float2 u  = make_float2(b.x - d.x, b.y - d.y);
    float2 t3 = make_float2(u.y, -u.x);            // -i*u
    A[a0]          = make_float2(t0.x + t2.x, t0.y + t2.y);
    A[a0 + st]     = cmul(make_float2(t1.x + t3.x, t1.y + t3.y), tw[f * q]);
    A[a0 + 2 * st] = cmul(make_float2(t0.x - t2.x, t0.y - t2.y), tw[2 * f * q]);
    A[a0 + 3 * st] = cmul(make_float2(t1.x - t3.x, t1.y - t3.y), tw[3 * f * q]);
}
// in-place radix-4 DIT butterfly (inv): exact inverse of bfly4_fwd (conj twiddles, IDFT4)
__device__ __forceinline__ void bfly4_inv(float2* A, int a0, int st, const float2* tw, int f, int q) {
    float2 w1 = tw[f * q], w2 = tw[2 * f * q], w3 = tw[3 * f * q];
    float2 y0 = A[a0];
    float2 y1 = cmul(A[a0 + st],     make_float2(w1.x, -w1.y));
    float2 y2 = cmul(A[a0 + 2 * st], make_float2(w2.x, -w2.y));
    float2 y3 = cmul(A[a0 + 3 * st], make_float2(w3.x, -w3.y));
    float2 t0 = make_float2(y0.x + y2.x, y0.y + y2.y);
    float2 t2 = make_float2(y0.x - y2.x, y0.y - y2.y);
    float2 t1 = make_float2(y1.x + y3.x, y1.y + y3.y);
    float2 u  = make_float2(y1.x - y3.x, y1.y - y3.y);
    A[a0]          = make_float2(t0.x + t1.x, t0.y + t1.y);
    A[a0 + st]     = make_float2(t2.x - u.y, t2.y + u.x);   // t2 + i*u
    A[a0 + 2 * st] = make_float2(t0.x - t1.x, t0.y - t1.y);
    A[a0 + 3 * st] = make_float2(t2.x + u.y, t2.y - u.x);   // t2 - i*u
}

// ---- gating ----
__global__ void k_prep(const float* __restrict__ g, const float* __restrict__ w_room,
                       const float* __restrict__ b_room, const float* __restrict__ w_mix,
                       const float* __restrict__ b_mix,
                       float* __restrict__ wroom, float* __restrict__ mixv) {
    int b = threadIdx.x;
    if (b >= BATCH) return;
    float logits[NROOM];
    for (int r = 0; r < NROOM; r++) logits[r] = b_room[r];
    float acc_mix = b_mix[0];
    for (int d = 0; d < DGATE; d++) {
        float gv = g[b * DGATE + d];
        for (int r = 0; r < NROOM; r++) logits[r] += gv * w_room[d * NROOM + r];
        acc_mix += gv * w_mix[d];
    }
    float m = logits[0];
    for (int r = 1; r < NROOM; r++) m = fmaxf(m, logits[r]);
    float s = 0.f;
    for (int r = 0; r < NROOM; r++) { logits[r] = expf(logits[r] - m); s += logits[r]; }
    float inv = 1.f / s;
    for (int r = 0; r < NROOM; r++) wroom[b * NROOM + r] = logits[r] * inv;
    mixv[b] = 1.f / (1.f + expf(-acc_mix));
}

// ---- build dry_b and time-domain mixed kernel K_b; pack Z_b = dry_b + i*K_b ----
__global__ void k_dry(const float* __restrict__ events, const int* __restrict__ indices,
                      const float* __restrict__ rooms, const float* __restrict__ wroom,
                      float* __restrict__ dryf, float2* __restrict__ C) {
    int gid = blockIdx.x * blockDim.x + threadIdx.x;
    int b = gid >> 14;
    int q = gid & 16383;
    int t0 = q << 2;
    float2* Cb = C + (size_t)b * L + t0;
    if (t0 < N_T) {
        const float* eb = events + (size_t)b * NEV * N_T;
        const int* ib = indices + b * NEV;
        float4 v = make_float4(0.f, 0.f, 0.f, 0.f);
#pragma unroll
        for (int e = 0; e < NEV; e++) {
            int n = t0 - (ib[e] << 8);
            if (n >= 0) {
                float4 ev = *(const float4*)(eb + e * N_T + n);
                v.x += ev.x; v.y += ev.y; v.z += ev.z; v.w += ev.w;
            }
        }
        const float* wb = wroom + b * NROOM;
        float4 kk = make_float4(0.f, 0.f, 0.f, 0.f);
#pragma unroll
        for (int r = 0; r < NROOM; r++) {
            float w = wb[r];
            float4 rv = *(const float4*)(rooms + (size_t)r * N_T + t0);
            kk.x += w * rv.x; kk.y += w * rv.y; kk.z += w * rv.z; kk.w += w * rv.w;
        }
        *(float4*)(dryf + (size_t)b * N_T + t0) = v;
        ((float4*)Cb)[0] = make_float4(v.x, kk.x, v.y, kk.y);
        ((float4*)Cb)[1] = make_float4(v.z, kk.z, v.w, kk.w);
    } else {
        ((float4*)Cb)[0] = make_float4(0.f, 0.f, 0.f, 0.f);
        ((float4*)Cb)[1] = make_float4(0.f, 0.f, 0.f, 0.f);
    }
}

// ---- forward col pass: in-place radix-4 DIF over n2 + big twiddle; dr4 row layout out ----
__global__ void k_fft_col_fwd(float2* __restrict__ C) {
    __shared__ float2 bufA[256 * NCP];
    __shared__ float2 tw[192];
    int t = threadIdx.x;
    int a = blockIdx.x >> 5;
    int c0 = (blockIdx.x & 31) * NC;
    float2* base = C + (size_t)a * L;
    if (t < 192) {
        float sv, cv;
        __sincosf(-TWO_PI * (float)t * (1.0f / 256.0f), &sv, &cv);
        tw[t] = make_float2(cv, sv);
    }
    for (int u = t; u < 1024; u += 256) {
        int cp = u & 3, e = u >> 2;
        float4 v = *(const float4*)(base + (c0 + 2 * cp) + (e << 8));
        bufA[e * NCP + 2 * cp]     = make_float2(v.x, v.y);
        bufA[e * NCP + 2 * cp + 1] = make_float2(v.z, v.w);
    }
    __syncthreads();
#pragma unroll
    for (int lm = 8; lm >= 2; lm -= 2) {
        int Q = 1 << (lm - 2);
        int f = 256 >> lm;
        for (int u = t; u < 512; u += 256) {
            int c = u & 7, qi = u >> 3;
            int q = qi & (Q - 1);
            int i0 = ((qi - q) << 2) + q;
            bfly4_fwd(bufA, i0 * NCP + c, Q * NCP, tw, f, q);
        }
        __syncthreads();
    }
    for (int u = t; u < 1024; u += 256) {
        int cp = u & 3, p = u >> 2;
        int k2 = dr4(p);                 // true frequency at this position
        int n1a = c0 + 2 * cp;
        float2 va = bufA[p * NCP + 2 * cp];
        float2 vb = bufA[p * NCP + 2 * cp + 1];
        int pha = (n1a * k2) & (L - 1);
        int phb = ((n1a + 1) * k2) & (L - 1);
        float sa, ca, sb, cb2;
        __sincosf(-TWO_PI * (float)pha * INV_L, &sa, &ca);
        __sincosf(-TWO_PI * (float)phb * INV_L, &sb, &cb2);
        float2 ra = cmul(va, make_float2(ca, sa));
        float2 rb = cmul(vb, make_float2(cb2, sb));
        *(float4*)(base + n1a + (p << 8)) = make_float4(ra.x, ra.y, rb.x, rb.y);
    }
}

// ---- pointwise unit: arrays 0/1 at LDS slots s / 4+s; Y written in place to slots 0..3 ----
__device__ __forceinline__ void pw_unit(float2* A, int sJ, int kJ, int sN, int kN) {
    float2 Z0j = A[sJ * ROWP + kJ],       Z0n = A[sN * ROWP + kN];
    float2 Z1j = A[(4 + sJ) * ROWP + kJ], Z1n = A[(4 + sN) * ROWP + kN];
    float2 D0 = make_float2(0.5f * (Z0j.x + Z0n.x), 0.5f * (Z0j.y - Z0n.y));
    float2 K0 = make_float2(0.5f * (Z0j.y + Z0n.y), 0.5f * (Z0n.x - Z0j.x));
    float2 D1 = make_float2(0.5f * (Z1j.x + Z1n.x), 0.5f * (Z1j.y - Z1n.y));
    float2 K1 = make_float2(0.5f * (Z1j.y + Z1n.y), 0.5f * (Z1n.x - Z1j.x));
    float2 W0 = cmul(D0, K0);
    float2 W1 = cmul(D1, K1);
    A[sJ * ROWP + kJ] = make_float2(W0.x - W1.y, W0.y + W1.x);
    A[sN * ROWP + kN] = make_float2(W0.x + W1.y, W1.x - W0.y);
}

// ---- fused row pass: fwd radix-4 DIF (8 rows) -> pointwise (in place) -> inv DIT (4 rows) ----
__global__ void k_rowpw(float2* __restrict__ C) {
    __shared__ float2 A[8 * ROWP];
    __shared__ float2 tw[192];
    int t = threadIdx.x;
    int p = blockIdx.x >> 6;
    int g = blockIdx.x & 63;
    int rows[4];
    if (g == 0) { rows[0] = 0; rows[1] = 1; rows[2] = 128; rows[3] = 255; }
    else        { rows[0] = 2 * g; rows[1] = 2 * g + 1; rows[2] = 256 - 2 * g; rows[3] = 255 - 2 * g; }
    if (t < 192) {
        float sv, cv;
        __sincosf(-TWO_PI * (float)t * (1.0f / 256.0f), &sv, &cv);
        tw[t] = make_float2(cv, sv);
    }
    float2* b0 = C + (size_t)(2 * p) * L;
    float2* b1 = b0 + L;
    for (int u = t; u < 1024; u += 256) {
        int slot = u >> 7;
        int f = (u & 127) << 1;
        const float2* arr = (slot < 4) ? b0 : b1;
        int grow = dr4(rows[slot & 3]);
        float4 v = *(const float4*)(arr + (grow << 8) + f);
        *(float4*)&A[slot * ROWP + f] = v;
    }
    __syncthreads();
    // forward: m=256,64 (row-slow mapping), m=16,4 (row-fast mapping)
#pragma unroll
    for (int lm = 8; lm >= 6; lm -= 2) {
        int Q = 1 << (lm - 2), f = 256 >> lm;
        for (int u = t; u < 512; u += 256) {
            int row = u >> 6, qi = u & 63;
            int q = qi & (Q - 1);
            int i0 = ((qi - q) << 2) + q;
            bfly4_fwd(A, row * ROWP + i0, Q, tw, f, q);
        }
        __syncthreads();
    }
#pragma unroll
    for (int lm = 4; lm >= 2; lm -= 2) {
        int Q = 1 << (lm - 2), f = 256 >> lm;
        for (int u = t; u < 512; u += 256) {
            int row = u & 7, qi = u >> 3;
            int q = qi & (Q - 1);
            int i0 = ((qi - q) << 2) + q;
            bfly4_fwd(A, row * ROWP + i0, Q, tw, f, q);
        }
        __syncthreads();
    }
    // pointwise in dr4 position domain: mirror rows pair (p, 255-p); row 0 needs dr4 orbits
    if (g) {
        pw_unit(A, 0, t, 2, 255 - t);
    } else {
        if (t == 0)      { pw_unit(A, 0, 0, 0, 0); pw_unit(A, 0, 2, 0, 2); }  // freqs 0 and 128
        else if (t < 128) pw_unit(A, 0, dr4(t), 0, dr4(256 - t));
        else              { int qq = t - 128; pw_unit(A, 2, qq, 2, 255 - qq); }
    }
    pw_unit(A, 1, t, 3, 255 - t);
    __syncthreads();
    // inverse on 4 packed rows: m=4,16 (row-fast), m=64,256 (row-slow)
#pragma unroll
    for (int lm = 2; lm <= 4; lm += 2) {
        int Q = 1 << (lm - 2), f = 256 >> lm;
        int row = t & 3, qi = t >> 2;
        int q = qi & (Q - 1);
        int i0 = ((qi - q) << 2) + q;
        bfly4_inv(A, row * ROWP + i0, Q, tw, f, q);
        __syncthreads();
    }
#pragma unroll
    for (int lm = 6; lm <= 8; lm += 2) {
        int Q = 1 << (lm - 2), f = 256 >> lm;
        int row = t >> 6, qi = t & 63;
        int q = qi & (Q - 1);
        int i0 = ((qi - q) << 2) + q;
        bfly4_inv(A, row * ROWP + i0, Q, tw, f, q);
        __syncthreads();
    }
    // inverse big twiddle (true row freq) + store to dr4 row position of array 2p
    for (int u = t; u < 512; u += 256) {
        int slot = u >> 7;
        int f = (u & 127) << 1;
        int r = rows[slot];
        float2 va = A[slot * ROWP + f];
        float2 vb = A[slot * ROWP + f + 1];
        int pha = (f * r) & (L - 1);
        int phb = ((f + 1) * r) & (L - 1);
        float sa, ca, sb, cb2;
        __sincosf(TWO_PI * (float)pha * INV_L, &sa, &ca);
        __sincosf(TWO_PI * (float)phb * INV_L, &sb, &cb2);
        float2 ra = cmul(va, make_float2(ca, sa));
        float2 rb = cmul(vb, make_float2(cb2, sb));
        *(float4*)(b0 + (dr4(r) << 8) + f) = make_float4(ra.x, ra.y, rb.x, rb.y);
    }
}

// ---- inverse col pass: radix-4 DIT consuming dr4 layout -> natural n2; fused mix+max ----
__global__ void k_fft_col_inv(float2* __restrict__ C, const float* __restrict__ dryf,
                              const float* __restrict__ mixv, float* __restrict__ out,
                              float* __restrict__ partial) {
    __shared__ float2 bufA[256 * NCP];
    __shared__ float2 tw[192];
    int t = threadIdx.x;
    int a = blockIdx.x >> 5;
    int cb = blockIdx.x & 31;
    int c0 = cb * NC;
    float2* base = C + (size_t)(2 * a) * L;
    if (t < 192) {
        float sv, cv;
        __sincosf(-TWO_PI * (float)t * (1.0f / 256.0f), &sv, &cv);
        tw[t] = make_float2(cv, sv);
    }
    for (int u = t; u < 1024; u += 256) {
        int cp = u & 3, e = u >> 2;
        float4 v = *(const float4*)(base + (c0 + 2 * cp) + (e << 8));
        bufA[e * NCP + 2 * cp]     = make_float2(v.x, v.y);
        bufA[e * NCP + 2 * cp + 1] = make_float2(v.z, v.w);
    }
    __syncthreads();
#pragma unroll
    for (int lm = 2; lm <= 8; lm += 2) {
        int Q = 1 << (lm - 2);
        int f = 256 >> lm;
        for (int u = t; u < 512; u += 256) {
            int c = u & 7, qi = u >> 3;
            int q = qi & (Q - 1);
            int i0 = ((qi - q) << 2) + q;
            bfly4_inv(bufA, i0 * NCP + c, Q * NCP, tw, f, q);
        }
        __syncthreads();
    }
    int b0 = 2 * a, b1 = 2 * a + 1;
    float mix0 = mixv[b0], mix1 = mixv[b1];
    float om0 = 1.f - mix0, om1 = 1.f - mix1;
    const float* dry0 = dryf + (size_t)b0 * N_T;
    const float* dry1 = dryf + (size_t)b1 * N_T;
    float* out0 = out + (size_t)b0 * N_T;
    float* out1 = out + (size_t)b1 * N_T;
    float m0 = -3.4e38f, m1 = -3.4e38f;
    for (int k = t; k < 1024; k += 256) {
        int cp = k & 3;
        int n2 = k >> 2;
        if (n2 < 128) {
            int pos = (c0 + 2 * cp) + (n2 << 8);
            float2 va = bufA[n2 * NCP + 2 * cp];
            float2 vb = bufA[n2 * NCP + 2 * cp + 1];
            float2 d0 = *(const float2*)(dry0 + pos);
            float2 d1 = *(const float2*)(dry1 + pos);
            float o0a = mix0 * (va.x * INV_L) + om0 * d0.x;
            float o0b = mix0 * (vb.x * INV_L) + om0 * d0.y;
            float o1a = mix1 * (va.y * INV_L) + om1 * d1.x;
            float o1b = mix1 * (vb.y * INV_L) + om1 * d1.y;
            *(float2*)(out0 + pos) = make_float2(o0a, o0b);
            *(float2*)(out1 + pos) = make_float2(o1a, o1b);
            m0 = fmaxf(m0, fmaxf(o0a, o0b));
            m1 = fmaxf(m1, fmaxf(o1a, o1b));
        }
    }
#pragma unroll
    for (int off = 32; off > 0; off >>= 1) {
        m0 = fmaxf(m0, __shfl_down(m0, off));
        m1 = fmaxf(m1, __shfl_down(m1, off));
    }
    __shared__ float sm0[4], sm1[4];
    if ((t & 63) == 0) { sm0[t >> 6] = m0; sm1[t >> 6] = m1; }
    __syncthreads();
    if (t == 0) {
        partial[b0 * 32 + cb] = fmaxf(fmaxf(sm0[0], sm0[1]), fmaxf(sm0[2], sm0[3]));
        partial[b1 * 32 + cb] = fmaxf(fmaxf(sm1[0], sm1[1]), fmaxf(sm1[2], sm1[3]));
    }
}

__global__ void k_norm(float* __restrict__ out, const float* __restrict__ partial) {
    int blk = blockIdx.x;
    int b = blk >> 5;
    int ch = blk & 31;
    __shared__ float smx;
    if (threadIdx.x < 32) {
        float p = partial[b * 32 + threadIdx.x];
#pragma unroll
        for (int off = 16; off > 0; off >>= 1) p = fmaxf(p, __shfl_down(p, off, 32));
        if (threadIdx.x == 0) smx = p;
    }
    __syncthreads();
    float inv = 1.f / (smx + 1e-8f);
    size_t base = (size_t)b * N_T + ch * 1024 + threadIdx.x * 4;
    float4 o = *(const float4*)(out + base);
    o.x *= inv; o.y *= inv; o.z *= inv; o.w *= inv;
    *(float4*)(out + base) = o;
}

extern "C" void kernel_launch(void* const* d_in, const int* in_sizes, int n_in,
                              void* d_out, int out_size, void* d_ws, size_t ws_size,
                              hipStream_t stream) {
    const float* events = (const float*)d_in[0];
    const int* indices = (const int*)d_in[1];
    const float* g      = (const float*)d_in[2];
    const float* rooms  = (const float*)d_in[3];
    const float* w_room = (const float*)d_in[4];
    const float* b_room = (const float*)d_in[5];
    const float* w_mix  = (const float*)d_in[6];
    const float* b_mix  = (const float*)d_in[7];
    float* out = (float*)d_out;

    char* ws = (char*)d_ws;
    float2* C = (float2*)ws;  // [64][65536] complex: Z_b = dry_b + i*K_b
    size_t off = (size_t)BATCH * L * sizeof(float2);
    float* dryf = (float*)(ws + off);
    off += (size_t)BATCH * N_T * sizeof(float);
    float* wroom = (float*)(ws + off);
    off += BATCH * NROOM * sizeof(float);
    float* mixv = (float*)(ws + off);
    off += BATCH * sizeof(float);
    float* partial = (float*)(ws + off);

    k_prep<<<1, 64, 0, stream>>>(g, w_room, b_room, w_mix, b_mix, wroom, mixv);
    k_dry<<<BATCH * (L / 4) / 256, 256, 0, stream>>>(events, indices, rooms, wroom, dryf, C);
    k_fft_col_fwd<<<BATCH * 32, 256, 0, stream>>>(C);
    k_rowpw<<<NPAIR * 64, 256, 0, stream>>>(C);
    k_fft_col_inv<<<NPAIR * 32, 256, 0, stream>>>(C, dryf, mixv, out, partial);
    k_norm<<<BATCH * 32, 256, 0, stream>>>(out, partial);
}

// Round 6
// 86.246 us; speedup vs baseline: 2.7553x; 1.2084x over previous
//
#include <hip/hip_runtime.h>
#include <math.h>

#define N_T 32768
#define L 65536
#define BATCH 64
#define NPAIR 32
#define NEV 8
#define NROOM 16
#define DGATE 128
#define ROWP 258
#define TP 17
#define TWO_PI 6.2831853071795864769f
#define INV_L (1.0f / 65536.0f)

__device__ __forceinline__ float2 cmul(float2 a, float2 b) {
    return make_float2(a.x * b.x - a.y * b.y, a.x * b.y + a.y * b.x);
}
// base-4 digit reversal of an 8-bit index (involution)
__device__ __forceinline__ int dr4(int p) {
    return ((p & 3) << 6) | ((p & 12) << 2) | ((p & 48) >> 2) | ((p & 192) >> 6);
}

// register radix-4 DIF butterfly (fwd)
__device__ __forceinline__ void bf4f(float2& a, float2& b, float2& c, float2& d,
                                     const float2* tw, int f, int q) {
    float2 t0 = make_float2(a.x + c.x, a.y + c.y);
    float2 t1 = make_float2(a.x - c.x, a.y - c.y);
    float2 t2 = make_float2(b.x + d.x, b.y + d.y);
    float2 u  = make_float2(b.x - d.x, b.y - d.y);
    float2 t3 = make_float2(u.y, -u.x);            // -i*u
    a = make_float2(t0.x + t2.x, t0.y + t2.y);
    b = cmul(make_float2(t1.x + t3.x, t1.y + t3.y), tw[f * q]);
    c = cmul(make_float2(t0.x - t2.x, t0.y - t2.y), tw[2 * f * q]);
    d = cmul(make_float2(t1.x - t3.x, t1.y - t3.y), tw[3 * f * q]);
}
// register radix-4 DIT butterfly (inv): exact inverse of bf4f
__device__ __forceinline__ void bf4i(float2& a, float2& b, float2& c, float2& d,
                                     const float2* tw, int f, int q) {
    float2 w1 = tw[f * q], w2 = tw[2 * f * q], w3 = tw[3 * f * q];
    float2 y0 = a;
    float2 y1 = cmul(b, make_float2(w1.x, -w1.y));
    float2 y2 = cmul(c, make_float2(w2.x, -w2.y));
    float2 y3 = cmul(d, make_float2(w3.x, -w3.y));
    float2 t0 = make_float2(y0.x + y2.x, y0.y + y2.y);
    float2 t2 = make_float2(y0.x - y2.x, y0.y - y2.y);
    float2 t1 = make_float2(y1.x + y3.x, y1.y + y3.y);
    float2 u  = make_float2(y1.x - y3.x, y1.y - y3.y);
    a = make_float2(t0.x + t1.x, t0.y + t1.y);
    b = make_float2(t2.x - u.y, t2.y + u.x);
    c = make_float2(t0.x - t1.x, t0.y - t1.y);
    d = make_float2(t2.x + u.y, t2.y - u.x);
}
__device__ __forceinline__ void bfly4_fwd(float2* A, int a0, int st, const float2* tw, int f, int q) {
    bf4f(A[a0], A[a0 + st], A[a0 + 2 * st], A[a0 + 3 * st], tw, f, q);
}
__device__ __forceinline__ void bfly4_inv(float2* A, int a0, int st, const float2* tw, int f, int q) {
    bf4i(A[a0], A[a0 + st], A[a0 + 2 * st], A[a0 + 3 * st], tw, f, q);
}

// ---- gating ----
__global__ void k_prep(const float* __restrict__ g, const float* __restrict__ w_room,
                       const float* __restrict__ b_room, const float* __restrict__ w_mix,
                       const float* __restrict__ b_mix,
                       float* __restrict__ wroom, float* __restrict__ mixv) {
    int b = threadIdx.x;
    if (b >= BATCH) return;
    float logits[NROOM];
    for (int r = 0; r < NROOM; r++) logits[r] = b_room[r];
    float acc_mix = b_mix[0];
    for (int d = 0; d < DGATE; d++) {
        float gv = g[b * DGATE + d];
        for (int r = 0; r < NROOM; r++) logits[r] += gv * w_room[d * NROOM + r];
        acc_mix += gv * w_mix[d];
    }
    float m = logits[0];
    for (int r = 1; r < NROOM; r++) m = fmaxf(m, logits[r]);
    float s = 0.f;
    for (int r = 0; r < NROOM; r++) { logits[r] = expf(logits[r] - m); s += logits[r]; }
    float inv = 1.f / s;
    for (int r = 0; r < NROOM; r++) wroom[b * NROOM + r] = logits[r] * inv;
    mixv[b] = 1.f / (1.f + expf(-acc_mix));
}

// ---- build dry_b and time-domain mixed kernel K_b; pack Z_b = dry_b + i*K_b ----
__global__ void k_dry(const float* __restrict__ events, const int* __restrict__ indices,
                      const float* __restrict__ rooms, const float* __restrict__ wroom,
                      float* __restrict__ dryf, float2* __restrict__ C) {
    int gid = blockIdx.x * blockDim.x + threadIdx.x;
    int b = gid >> 14;
    int q = gid & 16383;
    int t0 = q << 2;
    float2* Cb = C + (size_t)b * L + t0;
    if (t0 < N_T) {
        const float* eb = events + (size_t)b * NEV * N_T;
        const int* ib = indices + b * NEV;
        float4 v = make_float4(0.f, 0.f, 0.f, 0.f);
#pragma unroll
        for (int e = 0; e < NEV; e++) {
            int n = t0 - (ib[e] << 8);
            if (n >= 0) {
                float4 ev = *(const float4*)(eb + e * N_T + n);
                v.x += ev.x; v.y += ev.y; v.z += ev.z; v.w += ev.w;
            }
        }
        const float* wb = wroom + b * NROOM;
        float4 kk = make_float4(0.f, 0.f, 0.f, 0.f);
#pragma unroll
        for (int r = 0; r < NROOM; r++) {
            float w = wb[r];
            float4 rv = *(const float4*)(rooms + (size_t)r * N_T + t0);
            kk.x += w * rv.x; kk.y += w * rv.y; kk.z += w * rv.z; kk.w += w * rv.w;
        }
        *(float4*)(dryf + (size_t)b * N_T + t0) = v;
        ((float4*)Cb)[0] = make_float4(v.x, kk.x, v.y, kk.y);
        ((float4*)Cb)[1] = make_float4(v.z, kk.z, v.w, kk.w);
    } else {
        ((float4*)Cb)[0] = make_float4(0.f, 0.f, 0.f, 0.f);
        ((float4*)Cb)[1] = make_float4(0.f, 0.f, 0.f, 0.f);
    }
}

// ---- forward col pass: register radix-4 (stages 64,16 | LDS transpose | 4,1) + big twiddle ----
__global__ void k_fft_col_fwd(float2* __restrict__ C) {
    __shared__ float2 T[256 * TP];
    __shared__ float2 tw[256];
    __shared__ float2 fine[256];
    int t = threadIdx.x;
    int a = blockIdx.x >> 4;
    int c0 = (blockIdx.x & 15) * 16;
    float2* base = C + (size_t)a * L;
    {
        float sv, cv;
        __sincosf(-TWO_PI * (float)t * (1.0f / 256.0f), &sv, &cv);
        tw[t] = make_float2(cv, sv);
        __sincosf(-TWO_PI * (float)t * INV_L, &sv, &cv);
        fine[t] = make_float2(cv, sv);
    }
    int j = t >> 4, c = t & 15;
    int n1 = c0 + c;
    float2 r[16];
#pragma unroll
    for (int m = 0; m < 16; m++) r[m] = base[n1 + ((j + 16 * m) << 8)];
    __syncthreads();
#pragma unroll
    for (int m0 = 0; m0 < 4; m0++) bf4f(r[m0], r[m0 + 4], r[m0 + 8], r[m0 + 12], tw, 1, j + 16 * m0);
#pragma unroll
    for (int h = 0; h < 4; h++) bf4f(r[4 * h], r[4 * h + 1], r[4 * h + 2], r[4 * h + 3], tw, 4, j);
#pragma unroll
    for (int m = 0; m < 16; m++) T[(j + 16 * m) * TP + c] = r[m];
    __syncthreads();
#pragma unroll
    for (int jj = 0; jj < 16; jj++) r[jj] = T[(jj + 16 * j) * TP + c];
#pragma unroll
    for (int q = 0; q < 4; q++) bf4f(r[q], r[q + 4], r[q + 8], r[q + 12], tw, 16, q);
#pragma unroll
    for (int h = 0; h < 4; h++) bf4f(r[4 * h], r[4 * h + 1], r[4 * h + 2], r[4 * h + 3], tw, 64, 0);
#pragma unroll
    for (int jj = 0; jj < 16; jj++) {
        int p = jj + 16 * j;
        int k2 = dr4(p);
        int ph = (n1 * k2) & (L - 1);
        float2 w = cmul(tw[ph >> 8], fine[ph & 255]);
        base[n1 + (p << 8)] = cmul(r[jj], w);
    }
}

// ---- pointwise unit (LDS form) ----
__device__ __forceinline__ void pw_unit(float2* A, int sJ, int kJ, int sN, int kN) {
    float2 Z0j = A[sJ * ROWP + kJ],       Z0n = A[sN * ROWP + kN];
    float2 Z1j = A[(4 + sJ) * ROWP + kJ], Z1n = A[(4 + sN) * ROWP + kN];
    float2 D0 = make_float2(0.5f * (Z0j.x + Z0n.x), 0.5f * (Z0j.y - Z0n.y));
    float2 K0 = make_float2(0.5f * (Z0j.y + Z0n.y), 0.5f * (Z0n.x - Z0j.x));
    float2 D1 = make_float2(0.5f * (Z1j.x + Z1n.x), 0.5f * (Z1j.y - Z1n.y));
    float2 K1 = make_float2(0.5f * (Z1j.y + Z1n.y), 0.5f * (Z1n.x - Z1j.x));
    float2 W0 = cmul(D0, K0);
    float2 W1 = cmul(D1, K1);
    A[sJ * ROWP + kJ] = make_float2(W0.x - W1.y, W0.y + W1.x);
    A[sN * ROWP + kN] = make_float2(W0.x + W1.y, W1.x - W0.y);
}

// ---- fused row pass: fwd radix-4 DIF (8 rows) -> pointwise -> inv DIT (4 rows) ----
__global__ void k_rowpw(float2* __restrict__ C) {
    __shared__ float2 A[8 * ROWP];
    __shared__ float2 tw[192];
    int t = threadIdx.x;
    int p = blockIdx.x >> 6;
    int g = blockIdx.x & 63;
    int rows[4];
    if (g == 0) { rows[0] = 0; rows[1] = 1; rows[2] = 128; rows[3] = 255; }
    else        { rows[0] = 2 * g; rows[1] = 2 * g + 1; rows[2] = 256 - 2 * g; rows[3] = 255 - 2 * g; }
    if (t < 192) {
        float sv, cv;
        __sincosf(-TWO_PI * (float)t * (1.0f / 256.0f), &sv, &cv);
        tw[t] = make_float2(cv, sv);
    }
    float2* b0 = C + (size_t)(2 * p) * L;
    float2* b1 = b0 + L;
    for (int u = t; u < 1024; u += 256) {
        int slot = u >> 7;
        int f = (u & 127) << 1;
        const float2* arr = (slot < 4) ? b0 : b1;
        int grow = dr4(rows[slot & 3]);
        float4 v = *(const float4*)(arr + (grow << 8) + f);
        *(float4*)&A[slot * ROWP + f] = v;
    }
    __syncthreads();
#pragma unroll
    for (int lm = 8; lm >= 6; lm -= 2) {
        int Q = 1 << (lm - 2), f = 256 >> lm;
        for (int u = t; u < 512; u += 256) {
            int row = u >> 6, qi = u & 63;
            int q = qi & (Q - 1);
            int i0 = ((qi - q) << 2) + q;
            bfly4_fwd(A, row * ROWP + i0, Q, tw, f, q);
        }
        __syncthreads();
    }
#pragma unroll
    for (int lm = 4; lm >= 2; lm -= 2) {
        int Q = 1 << (lm - 2), f = 256 >> lm;
        for (int u = t; u < 512; u += 256) {
            int row = u & 7, qi = u >> 3;
            int q = qi & (Q - 1);
            int i0 = ((qi - q) << 2) + q;
            bfly4_fwd(A, row * ROWP + i0, Q, tw, f, q);
        }
        __syncthreads();
    }
    if (g) {
        pw_unit(A, 0, t, 2, 255 - t);
    } else {
        if (t == 0)      { pw_unit(A, 0, 0, 0, 0); pw_unit(A, 0, 2, 0, 2); }
        else if (t < 128) pw_unit(A, 0, dr4(t), 0, dr4(256 - t));
        else              { int qq = t - 128; pw_unit(A, 2, qq, 2, 255 - qq); }
    }
    pw_unit(A, 1, t, 3, 255 - t);
    __syncthreads();
#pragma unroll
    for (int lm = 2; lm <= 4; lm += 2) {
        int Q = 1 << (lm - 2), f = 256 >> lm;
        int row = t & 3, qi = t >> 2;
        int q = qi & (Q - 1);
        int i0 = ((qi - q) << 2) + q;
        bfly4_inv(A, row * ROWP + i0, Q, tw, f, q);
        __syncthreads();
    }
#pragma unroll
    for (int lm = 6; lm <= 8; lm += 2) {
        int Q = 1 << (lm - 2), f = 256 >> lm;
        int row = t >> 6, qi = t & 63;
        int q = qi & (Q - 1);
        int i0 = ((qi - q) << 2) + q;
        bfly4_inv(A, row * ROWP + i0, Q, tw, f, q);
        __syncthreads();
    }
    for (int u = t; u < 512; u += 256) {
        int slot = u >> 7;
        int f = (u & 127) << 1;
        int r = rows[slot];
        float2 va = A[slot * ROWP + f];
        float2 vb = A[slot * ROWP + f + 1];
        int pha = (f * r) & (L - 1);
        int phb = ((f + 1) * r) & (L - 1);
        float sa, ca, sb, cb2;
        __sincosf(TWO_PI * (float)pha * INV_L, &sa, &ca);
        __sincosf(TWO_PI * (float)phb * INV_L, &sb, &cb2);
        float2 ra = cmul(va, make_float2(ca, sa));
        float2 rb = cmul(vb, make_float2(cb2, sb));
        *(float4*)(b0 + (dr4(r) << 8) + f) = make_float4(ra.x, ra.y, rb.x, rb.y);
    }
}

// ---- inverse col pass (register): stages 1,4 | transpose | 16,64; fused mix+max ----
__global__ void k_fft_col_inv(float2* __restrict__ C, const float* __restrict__ dryf,
                              const float* __restrict__ mixv, float* __restrict__ out,
                              float* __restrict__ partial) {
    __shared__ float2 T[256 * TP];
    __shared__ float2 tw[256];
    __shared__ float sm0[4], sm1[4];
    int t = threadIdx.x;
    int a = blockIdx.x >> 4;
    int cbg = blockIdx.x & 15;
    int c0 = cbg * 16;
    float2* base = C + (size_t)(2 * a) * L;
    {
        float sv, cv;
        __sincosf(-TWO_PI * (float)t * (1.0f / 256.0f), &sv, &cv);
        tw[t] = make_float2(cv, sv);
    }
    int j = t >> 4, c = t & 15;
    int n1 = c0 + c;
    float2 r[16];
#pragma unroll
    for (int jj = 0; jj < 16; jj++) r[jj] = base[n1 + ((jj + 16 * j) << 8)];
    __syncthreads();
#pragma unroll
    for (int h = 0; h < 4; h++) bf4i(r[4 * h], r[4 * h + 1], r[4 * h + 2], r[4 * h + 3], tw, 64, 0);
#pragma unroll
    for (int q = 0; q < 4; q++) bf4i(r[q], r[q + 4], r[q + 8], r[q + 12], tw, 16, q);
#pragma unroll
    for (int jj = 0; jj < 16; jj++) T[(jj + 16 * j) * TP + c] = r[jj];
    __syncthreads();
#pragma unroll
    for (int m = 0; m < 16; m++) r[m] = T[(j + 16 * m) * TP + c];
#pragma unroll
    for (int h = 0; h < 4; h++) bf4i(r[4 * h], r[4 * h + 1], r[4 * h + 2], r[4 * h + 3], tw, 4, j);
#pragma unroll
    for (int m0 = 0; m0 < 4; m0++) bf4i(r[m0], r[m0 + 4], r[m0 + 8], r[m0 + 12], tw, 1, j + 16 * m0);
    int b0 = 2 * a, b1 = 2 * a + 1;
    float mix0 = mixv[b0], mix1 = mixv[b1];
    float om0 = 1.f - mix0, om1 = 1.f - mix1;
    const float* dry0 = dryf + (size_t)b0 * N_T;
    const float* dry1 = dryf + (size_t)b1 * N_T;
    float* out0 = out + (size_t)b0 * N_T;
    float* out1 = out + (size_t)b1 * N_T;
    float m0 = -3.4e38f, m1 = -3.4e38f;
#pragma unroll
    for (int m = 0; m < 8; m++) {
        int pos = n1 + ((j + 16 * m) << 8);
        float d0 = dry0[pos], d1 = dry1[pos];
        float o0 = mix0 * (r[m].x * INV_L) + om0 * d0;
        float o1 = mix1 * (r[m].y * INV_L) + om1 * d1;
        out0[pos] = o0;
        out1[pos] = o1;
        m0 = fmaxf(m0, o0);
        m1 = fmaxf(m1, o1);
    }
#pragma unroll
    for (int off = 32; off > 0; off >>= 1) {
        m0 = fmaxf(m0, __shfl_down(m0, off));
        m1 = fmaxf(m1, __shfl_down(m1, off));
    }
    if ((t & 63) == 0) { sm0[t >> 6] = m0; sm1[t >> 6] = m1; }
    __syncthreads();
    if (t == 0) {
        partial[b0 * 16 + cbg] = fmaxf(fmaxf(sm0[0], sm0[1]), fmaxf(sm0[2], sm0[3]));
        partial[b1 * 16 + cbg] = fmaxf(fmaxf(sm1[0], sm1[1]), fmaxf(sm1[2], sm1[3]));
    }
}

__global__ void k_norm(float* __restrict__ out, const float* __restrict__ partial) {
    int blk = blockIdx.x;
    int b = blk >> 5;
    int ch = blk & 31;
    __shared__ float smx;
    if (threadIdx.x < 16) {
        float p = partial[b * 16 + threadIdx.x];
#pragma unroll
        for (int off = 8; off > 0; off >>= 1) p = fmaxf(p, __shfl_down(p, off, 16));
        if (threadIdx.x == 0) smx = p;
    }
    __syncthreads();
    float inv = 1.f / (smx + 1e-8f);
    size_t base = (size_t)b * N_T + ch * 1024 + threadIdx.x * 4;
    float4 o = *(const float4*)(out + base);
    o.x *= inv; o.y *= inv; o.z *= inv; o.w *= inv;
    *(float4*)(out + base) = o;
}

extern "C" void kernel_launch(void* const* d_in, const int* in_sizes, int n_in,
                              void* d_out, int out_size, void* d_ws, size_t ws_size,
                              hipStream_t stream) {
    const float* events = (const float*)d_in[0];
    const int* indices = (const int*)d_in[1];
    const float* g      = (const float*)d_in[2];
    const float* rooms  = (const float*)d_in[3];
    const float* w_room = (const float*)d_in[4];
    const float* b_room = (const float*)d_in[5];
    const float* w_mix  = (const float*)d_in[6];
    const float* b_mix  = (const float*)d_in[7];
    float* out = (float*)d_out;

    char* ws = (char*)d_ws;
    float2* C = (float2*)ws;  // [64][65536] complex: Z_b = dry_b + i*K_b
    size_t off = (size_t)BATCH * L * sizeof(float2);
    float* dryf = (float*)(ws + off);
    off += (size_t)BATCH * N_T * sizeof(float);
    float* wroom = (float*)(ws + off);
    off += BATCH * NROOM * sizeof(float);
    float* mixv = (float*)(ws + off);
    off += BATCH * sizeof(float);
    float* partial = (float*)(ws + off);

    k_prep<<<1, 64, 0, stream>>>(g, w_room, b_room, w_mix, b_mix, wroom, mixv);
    k_dry<<<BATCH * (L / 4) / 256, 256, 0, stream>>>(events, indices, rooms, wroom, dryf, C);
    k_fft_col_fwd<<<BATCH * 16, 256, 0, stream>>>(C);
    k_rowpw<<<NPAIR * 64, 256, 0, stream>>>(C);
    k_fft_col_inv<<<NPAIR * 16, 256, 0, stream>>>(C, dryf, mixv, out, partial);
    k_norm<<<BATCH * 32, 256, 0, stream>>>(out, partial);
}

// Round 7
// 81.276 us; speedup vs baseline: 2.9238x; 1.0611x over previous
//
#include <hip/hip_runtime.h>
#include <math.h>

#define N_T 32768
#define L 65536
#define BATCH 64
#define NPAIR 32
#define NEV 8
#define NROOM 16
#define DGATE 128
#define ROWP 258
#define TP 17
#define TWO_PI 6.2831853071795864769f
#define INV_L (1.0f / 65536.0f)

__device__ __forceinline__ float2 cmul(float2 a, float2 b) {
    return make_float2(a.x * b.x - a.y * b.y, a.x * b.y + a.y * b.x);
}
// base-4 digit reversal of an 8-bit index (involution)
__device__ __forceinline__ int dr4(int p) {
    return ((p & 3) << 6) | ((p & 12) << 2) | ((p & 48) >> 2) | ((p & 192) >> 6);
}

// register radix-4 DIF butterfly (fwd)
__device__ __forceinline__ void bf4f(float2& a, float2& b, float2& c, float2& d,
                                     const float2* tw, int f, int q) {
    float2 t0 = make_float2(a.x + c.x, a.y + c.y);
    float2 t1 = make_float2(a.x - c.x, a.y - c.y);
    float2 t2 = make_float2(b.x + d.x, b.y + d.y);
    float2 u  = make_float2(b.x - d.x, b.y - d.y);
    float2 t3 = make_float2(u.y, -u.x);            // -i*u
    a = make_float2(t0.x + t2.x, t0.y + t2.y);
    b = cmul(make_float2(t1.x + t3.x, t1.y + t3.y), tw[f * q]);
    c = cmul(make_float2(t0.x - t2.x, t0.y - t2.y), tw[2 * f * q]);
    d = cmul(make_float2(t1.x - t3.x, t1.y - t3.y), tw[3 * f * q]);
}
// register radix-4 DIT butterfly (inv): exact inverse of bf4f
__device__ __forceinline__ void bf4i(float2& a, float2& b, float2& c, float2& d,
                                     const float2* tw, int f, int q) {
    float2 w1 = tw[f * q], w2 = tw[2 * f * q], w3 = tw[3 * f * q];
    float2 y0 = a;
    float2 y1 = cmul(b, make_float2(w1.x, -w1.y));
    float2 y2 = cmul(c, make_float2(w2.x, -w2.y));
    float2 y3 = cmul(d, make_float2(w3.x, -w3.y));
    float2 t0 = make_float2(y0.x + y2.x, y0.y + y2.y);
    float2 t2 = make_float2(y0.x - y2.x, y0.y - y2.y);
    float2 t1 = make_float2(y1.x + y3.x, y1.y + y3.y);
    float2 u  = make_float2(y1.x - y3.x, y1.y - y3.y);
    a = make_float2(t0.x + t1.x, t0.y + t1.y);
    b = make_float2(t2.x - u.y, t2.y + u.x);
    c = make_float2(t0.x - t1.x, t0.y - t1.y);
    d = make_float2(t2.x + u.y, t2.y - u.x);
}
__device__ __forceinline__ void bfly4_fwd(float2* A, int a0, int st, const float2* tw, int f, int q) {
    bf4f(A[a0], A[a0 + st], A[a0 + 2 * st], A[a0 + 3 * st], tw, f, q);
}
__device__ __forceinline__ void bfly4_inv(float2* A, int a0, int st, const float2* tw, int f, int q) {
    bf4i(A[a0], A[a0 + st], A[a0 + 2 * st], A[a0 + 3 * st], tw, f, q);
}

// ---- gating ----
__global__ void k_prep(const float* __restrict__ g, const float* __restrict__ w_room,
                       const float* __restrict__ b_room, const float* __restrict__ w_mix,
                       const float* __restrict__ b_mix,
                       float* __restrict__ wroom, float* __restrict__ mixv) {
    int b = threadIdx.x;
    if (b >= BATCH) return;
    float logits[NROOM];
    for (int r = 0; r < NROOM; r++) logits[r] = b_room[r];
    float acc_mix = b_mix[0];
    for (int d = 0; d < DGATE; d++) {
        float gv = g[b * DGATE + d];
        for (int r = 0; r < NROOM; r++) logits[r] += gv * w_room[d * NROOM + r];
        acc_mix += gv * w_mix[d];
    }
    float m = logits[0];
    for (int r = 1; r < NROOM; r++) m = fmaxf(m, logits[r]);
    float s = 0.f;
    for (int r = 0; r < NROOM; r++) { logits[r] = expf(logits[r] - m); s += logits[r]; }
    float inv = 1.f / s;
    for (int r = 0; r < NROOM; r++) wroom[b * NROOM + r] = logits[r] * inv;
    mixv[b] = 1.f / (1.f + expf(-acc_mix));
}

// ---- fused: build dry+K tile (STEP==row stride => shift is a pure row offset within a
// column block), write dryf, then register radix-4 fwd col FFT + big twiddle ----
__global__ void k_fwd(const float* __restrict__ events, const int* __restrict__ indices,
                      const float* __restrict__ rooms, const float* __restrict__ wroom,
                      float* __restrict__ dryf, float2* __restrict__ C) {
    __shared__ float2 T[256 * TP];       // transpose buffer; front 16 KB reused as staging
    __shared__ float2 tw[256];
    __shared__ float2 fine[256];
    int t = threadIdx.x;
    int a = blockIdx.x >> 4;             // batch
    int c0 = (blockIdx.x & 15) * 16;     // column group
    float2* base = C + (size_t)a * L;
    {
        float sv, cv;
        __sincosf(-TWO_PI * (float)t * (1.0f / 256.0f), &sv, &cv);
        tw[t] = make_float2(cv, sv);
        __sincosf(-TWO_PI * (float)t * INV_L, &sv, &cv);
        fine[t] = make_float2(cv, sv);
    }
    float* dtile = (float*)T;            // [128][16] dry
    float* ktile = dtile + 128 * 16;     // [128][16] K
    const float* eb = events + (size_t)a * NEV * N_T;
    const int* ib = indices + a * NEV;
    const float* wb = wroom + a * NROOM;
    // unit u = n2*4 + qc (qc = float4-column); thread owns u and u+256
    int n2a = t >> 2, qa = (t & 3) << 2;
    int n2b = n2a + 64, qb = qa;
    float4 d0 = make_float4(0.f, 0.f, 0.f, 0.f), d1 = d0, k0 = d0, k1 = d0;
#pragma unroll
    for (int e = 0; e < NEV; e++) {
        int s = ib[e];
        const float* er = eb + e * N_T + c0;
        if (n2a >= s) {
            float4 v = *(const float4*)(er + qa + ((n2a - s) << 8));
            d0.x += v.x; d0.y += v.y; d0.z += v.z; d0.w += v.w;
        }
        if (n2b >= s) {
            float4 v = *(const float4*)(er + qb + ((n2b - s) << 8));
            d1.x += v.x; d1.y += v.y; d1.z += v.z; d1.w += v.w;
        }
    }
#pragma unroll
    for (int r = 0; r < NROOM; r++) {
        float w = wb[r];
        const float* rr = rooms + (size_t)r * N_T + c0;
        float4 v0 = *(const float4*)(rr + qa + (n2a << 8));
        float4 v1 = *(const float4*)(rr + qb + (n2b << 8));
        k0.x += w * v0.x; k0.y += w * v0.y; k0.z += w * v0.z; k0.w += w * v0.w;
        k1.x += w * v1.x; k1.y += w * v1.y; k1.z += w * v1.z; k1.w += w * v1.w;
    }
    float* db = dryf + (size_t)a * N_T + c0;
    *(float4*)(db + qa + (n2a << 8)) = d0;
    *(float4*)(db + qb + (n2b << 8)) = d1;
    *(float4*)&dtile[n2a * 16 + qa] = d0;
    *(float4*)&dtile[n2b * 16 + qb] = d1;
    *(float4*)&ktile[n2a * 16 + qa] = k0;
    *(float4*)&ktile[n2b * 16 + qb] = k1;
    __syncthreads();
    int j = t >> 4, c = t & 15;
    int n1 = c0 + c;
    float2 r[16];
#pragma unroll
    for (int m = 0; m < 8; m++) {
        int n2 = j + 16 * m;             // < 128 always (j<16, m<8)
        r[m] = make_float2(dtile[n2 * 16 + c], ktile[n2 * 16 + c]);
    }
#pragma unroll
    for (int m = 8; m < 16; m++) r[m] = make_float2(0.f, 0.f);
    // stages 1-2 in registers
#pragma unroll
    for (int m0 = 0; m0 < 4; m0++) bf4f(r[m0], r[m0 + 4], r[m0 + 8], r[m0 + 12], tw, 1, j + 16 * m0);
#pragma unroll
    for (int h = 0; h < 4; h++) bf4f(r[4 * h], r[4 * h + 1], r[4 * h + 2], r[4 * h + 3], tw, 4, j);
    __syncthreads();                     // staging region dead; safe to overwrite T
#pragma unroll
    for (int m = 0; m < 16; m++) T[(j + 16 * m) * TP + c] = r[m];
    __syncthreads();
#pragma unroll
    for (int jj = 0; jj < 16; jj++) r[jj] = T[(jj + 16 * j) * TP + c];
#pragma unroll
    for (int q = 0; q < 4; q++) bf4f(r[q], r[q + 4], r[q + 8], r[q + 12], tw, 16, q);
#pragma unroll
    for (int h = 0; h < 4; h++) bf4f(r[4 * h], r[4 * h + 1], r[4 * h + 2], r[4 * h + 3], tw, 64, 0);
#pragma unroll
    for (int jj = 0; jj < 16; jj++) {
        int p = jj + 16 * j;
        int k2 = dr4(p);
        int ph = (n1 * k2) & (L - 1);
        float2 w = cmul(tw[ph >> 8], fine[ph & 255]);
        base[n1 + (p << 8)] = cmul(r[jj], w);
    }
}

// ---- pointwise unit (LDS form) ----
__device__ __forceinline__ void pw_unit(float2* A, int sJ, int kJ, int sN, int kN) {
    float2 Z0j = A[sJ * ROWP + kJ],       Z0n = A[sN * ROWP + kN];
    float2 Z1j = A[(4 + sJ) * ROWP + kJ], Z1n = A[(4 + sN) * ROWP + kN];
    float2 D0 = make_float2(0.5f * (Z0j.x + Z0n.x), 0.5f * (Z0j.y - Z0n.y));
    float2 K0 = make_float2(0.5f * (Z0j.y + Z0n.y), 0.5f * (Z0n.x - Z0j.x));
    float2 D1 = make_float2(0.5f * (Z1j.x + Z1n.x), 0.5f * (Z1j.y - Z1n.y));
    float2 K1 = make_float2(0.5f * (Z1j.y + Z1n.y), 0.5f * (Z1n.x - Z1j.x));
    float2 W0 = cmul(D0, K0);
    float2 W1 = cmul(D1, K1);
    A[sJ * ROWP + kJ] = make_float2(W0.x - W1.y, W0.y + W1.x);
    A[sN * ROWP + kN] = make_float2(W0.x + W1.y, W1.x - W0.y);
}

// ---- fused row pass: fwd radix-4 DIF (8 rows) -> pointwise -> inv DIT (4 rows) ----
__global__ void k_rowpw(float2* __restrict__ C) {
    __shared__ float2 A[8 * ROWP];
    __shared__ float2 tw[192];
    int t = threadIdx.x;
    int p = blockIdx.x >> 6;
    int g = blockIdx.x & 63;
    int rows[4];
    if (g == 0) { rows[0] = 0; rows[1] = 1; rows[2] = 128; rows[3] = 255; }
    else        { rows[0] = 2 * g; rows[1] = 2 * g + 1; rows[2] = 256 - 2 * g; rows[3] = 255 - 2 * g; }
    if (t < 192) {
        float sv, cv;
        __sincosf(-TWO_PI * (float)t * (1.0f / 256.0f), &sv, &cv);
        tw[t] = make_float2(cv, sv);
    }
    float2* b0 = C + (size_t)(2 * p) * L;
    float2* b1 = b0 + L;
    for (int u = t; u < 1024; u += 256) {
        int slot = u >> 7;
        int f = (u & 127) << 1;
        const float2* arr = (slot < 4) ? b0 : b1;
        int grow = dr4(rows[slot & 3]);
        float4 v = *(const float4*)(arr + (grow << 8) + f);
        *(float4*)&A[slot * ROWP + f] = v;
    }
    __syncthreads();
#pragma unroll
    for (int lm = 8; lm >= 6; lm -= 2) {
        int Q = 1 << (lm - 2), f = 256 >> lm;
        for (int u = t; u < 512; u += 256) {
            int row = u >> 6, qi = u & 63;
            int q = qi & (Q - 1);
            int i0 = ((qi - q) << 2) + q;
            bfly4_fwd(A, row * ROWP + i0, Q, tw, f, q);
        }
        __syncthreads();
    }
#pragma unroll
    for (int lm = 4; lm >= 2; lm -= 2) {
        int Q = 1 << (lm - 2), f = 256 >> lm;
        for (int u = t; u < 512; u += 256) {
            int row = u & 7, qi = u >> 3;
            int q = qi & (Q - 1);
            int i0 = ((qi - q) << 2) + q;
            bfly4_fwd(A, row * ROWP + i0, Q, tw, f, q);
        }
        __syncthreads();
    }
    if (g) {
        pw_unit(A, 0, t, 2, 255 - t);
    } else {
        if (t == 0)      { pw_unit(A, 0, 0, 0, 0); pw_unit(A, 0, 2, 0, 2); }
        else if (t < 128) pw_unit(A, 0, dr4(t), 0, dr4(256 - t));
        else              { int qq = t - 128; pw_unit(A, 2, qq, 2, 255 - qq); }
    }
    pw_unit(A, 1, t, 3, 255 - t);
    __syncthreads();
#pragma unroll
    for (int lm = 2; lm <= 4; lm += 2) {
        int Q = 1 << (lm - 2), f = 256 >> lm;
        int row = t & 3, qi = t >> 2;
        int q = qi & (Q - 1);
        int i0 = ((qi - q) << 2) + q;
        bfly4_inv(A, row * ROWP + i0, Q, tw, f, q);
        __syncthreads();
    }
#pragma unroll
    for (int lm = 6; lm <= 8; lm += 2) {
        int Q = 1 << (lm - 2), f = 256 >> lm;
        int row = t >> 6, qi = t & 63;
        int q = qi & (Q - 1);
        int i0 = ((qi - q) << 2) + q;
        bfly4_inv(A, row * ROWP + i0, Q, tw, f, q);
        __syncthreads();
    }
    for (int u = t; u < 512; u += 256) {
        int slot = u >> 7;
        int f = (u & 127) << 1;
        int r = rows[slot];
        float2 va = A[slot * ROWP + f];
        float2 vb = A[slot * ROWP + f + 1];
        int pha = (f * r) & (L - 1);
        int phb = ((f + 1) * r) & (L - 1);
        float sa, ca, sb, cb2;
        __sincosf(TWO_PI * (float)pha * INV_L, &sa, &ca);
        __sincosf(TWO_PI * (float)phb * INV_L, &sb, &cb2);
        float2 ra = cmul(va, make_float2(ca, sa));
        float2 rb = cmul(vb, make_float2(cb2, sb));
        *(float4*)(b0 + (dr4(r) << 8) + f) = make_float4(ra.x, ra.y, rb.x, rb.y);
    }
}

// ---- inverse col pass (register): stages 1,4 | transpose | 16,64; fused mix+max ----
__global__ void k_fft_col_inv(float2* __restrict__ C, const float* __restrict__ dryf,
                              const float* __restrict__ mixv, float* __restrict__ out,
                              float* __restrict__ partial) {
    __shared__ float2 T[256 * TP];
    __shared__ float2 tw[256];
    __shared__ float sm0[4], sm1[4];
    int t = threadIdx.x;
    int a = blockIdx.x >> 4;
    int cbg = blockIdx.x & 15;
    int c0 = cbg * 16;
    float2* base = C + (size_t)(2 * a) * L;
    {
        float sv, cv;
        __sincosf(-TWO_PI * (float)t * (1.0f / 256.0f), &sv, &cv);
        tw[t] = make_float2(cv, sv);
    }
    int j = t >> 4, c = t & 15;
    int n1 = c0 + c;
    float2 r[16];
#pragma unroll
    for (int jj = 0; jj < 16; jj++) r[jj] = base[n1 + ((jj + 16 * j) << 8)];
    __syncthreads();
#pragma unroll
    for (int h = 0; h < 4; h++) bf4i(r[4 * h], r[4 * h + 1], r[4 * h + 2], r[4 * h + 3], tw, 64, 0);
#pragma unroll
    for (int q = 0; q < 4; q++) bf4i(r[q], r[q + 4], r[q + 8], r[q + 12], tw, 16, q);
#pragma unroll
    for (int jj = 0; jj < 16; jj++) T[(jj + 16 * j) * TP + c] = r[jj];
    __syncthreads();
#pragma unroll
    for (int m = 0; m < 16; m++) r[m] = T[(j + 16 * m) * TP + c];
#pragma unroll
    for (int h = 0; h < 4; h++) bf4i(r[4 * h], r[4 * h + 1], r[4 * h + 2], r[4 * h + 3], tw, 4, j);
#pragma unroll
    for (int m0 = 0; m0 < 4; m0++) bf4i(r[m0], r[m0 + 4], r[m0 + 8], r[m0 + 12], tw, 1, j + 16 * m0);
    int b0 = 2 * a, b1 = 2 * a + 1;
    float mix0 = mixv[b0], mix1 = mixv[b1];
    float om0 = 1.f - mix0, om1 = 1.f - mix1;
    const float* dry0 = dryf + (size_t)b0 * N_T;
    const float* dry1 = dryf + (size_t)b1 * N_T;
    float* out0 = out + (size_t)b0 * N_T;
    float* out1 = out + (size_t)b1 * N_T;
    float m0 = -3.4e38f, m1 = -3.4e38f;
#pragma unroll
    for (int m = 0; m < 8; m++) {
        int pos = n1 + ((j + 16 * m) << 8);
        float d0 = dry0[pos], d1 = dry1[pos];
        float o0 = mix0 * (r[m].x * INV_L) + om0 * d0;
        float o1 = mix1 * (r[m].y * INV_L) + om1 * d1;
        out0[pos] = o0;
        out1[pos] = o1;
        m0 = fmaxf(m0, o0);
        m1 = fmaxf(m1, o1);
    }
#pragma unroll
    for (int off = 32; off > 0; off >>= 1) {
        m0 = fmaxf(m0, __shfl_down(m0, off));
        m1 = fmaxf(m1, __shfl_down(m1, off));
    }
    if ((t & 63) == 0) { sm0[t >> 6] = m0; sm1[t >> 6] = m1; }
    __syncthreads();
    if (t == 0) {
        partial[b0 * 16 + cbg] = fmaxf(fmaxf(sm0[0], sm0[1]), fmaxf(sm0[2], sm0[3]));
        partial[b1 * 16 + cbg] = fmaxf(fmaxf(sm1[0], sm1[1]), fmaxf(sm1[2], sm1[3]));
    }
}

__global__ void k_norm(float* __restrict__ out, const float* __restrict__ partial) {
    int blk = blockIdx.x;
    int b = blk >> 5;
    int ch = blk & 31;
    __shared__ float smx;
    if (threadIdx.x < 16) {
        float p = partial[b * 16 + threadIdx.x];
#pragma unroll
        for (int off = 8; off > 0; off >>= 1) p = fmaxf(p, __shfl_down(p, off, 16));
        if (threadIdx.x == 0) smx = p;
    }
    __syncthreads();
    float inv = 1.f / (smx + 1e-8f);
    size_t base = (size_t)b * N_T + ch * 1024 + threadIdx.x * 4;
    float4 o = *(const float4*)(out + base);
    o.x *= inv; o.y *= inv; o.z *= inv; o.w *= inv;
    *(float4*)(out + base) = o;
}

extern "C" void kernel_launch(void* const* d_in, const int* in_sizes, int n_in,
                              void* d_out, int out_size, void* d_ws, size_t ws_size,
                              hipStream_t stream) {
    const float* events = (const float*)d_in[0];
    const int* indices = (const int*)d_in[1];
    const float* g      = (const float*)d_in[2];
    const float* rooms  = (const float*)d_in[3];
    const float* w_room = (const float*)d_in[4];
    const float* b_room = (const float*)d_in[5];
    const float* w_mix  = (const float*)d_in[6];
    const float* b_mix  = (const float*)d_in[7];
    float* out = (float*)d_out;

    char* ws = (char*)d_ws;
    float2* C = (float2*)ws;  // [64][65536] complex: Z_b = dry_b + i*K_b (spectral)
    size_t off = (size_t)BATCH * L * sizeof(float2);
    float* dryf = (float*)(ws + off);
    off += (size_t)BATCH * N_T * sizeof(float);
    float* wroom = (float*)(ws + off);
    off += BATCH * NROOM * sizeof(float);
    float* mixv = (float*)(ws + off);
    off += BATCH * sizeof(float);
    float* partial = (float*)(ws + off);

    k_prep<<<1, 64, 0, stream>>>(g, w_room, b_room, w_mix, b_mix, wroom, mixv);
    k_fwd<<<BATCH * 16, 256, 0, stream>>>(events, indices, rooms, wroom, dryf, C);
    k_rowpw<<<NPAIR * 64, 256, 0, stream>>>(C);
    k_fft_col_inv<<<NPAIR * 16, 256, 0, stream>>>(C, dryf, mixv, out, partial);
    k_norm<<<BATCH * 32, 256, 0, stream>>>(out, partial);
}